// Round 1
// baseline (2059.212 us; speedup 1.0000x reference)
//
#include <hip/hip_runtime.h>
#include <stdint.h>

#define NN 32
#define CC 32
#define VV 400
#define LL 12
#define TT 512
#define AL 0.05f
#define OM 0.95f

__device__ __forceinline__ float bflo(uint32_t u){ union {uint32_t i; float f;} t; t.i = u << 16; return t.f; }
__device__ __forceinline__ float bfhi(uint32_t u){ union {uint32_t i; float f;} t; t.i = u & 0xffff0000u; return t.f; }
__device__ __forceinline__ uint32_t f2bf(float f){ union {float f; uint32_t i;} t; t.f = f; return (t.i + 0x7fffu + ((t.i >> 16) & 1u)) >> 16; }
__device__ __forceinline__ float bf2f(uint16_t h){ union {uint32_t i; float f;} t; t.i = ((uint32_t)h) << 16; return t.f; }

// acc += dot(2 bf16 packed in u, arr[k..k+1])
#define D2(u, arr, k, acc) { acc += bflo(u)*arr[k] + bfhi(u)*arr[(k)+1]; }
// arr[k..k+1] += p * (2 bf16 packed in u)
#define A2(u, k, p, arr)   { arr[k] += (p)*bflo(u); arr[(k)+1] += (p)*bfhi(u); }

// computes a = A[v,w] = x1[:,v].x2w  and  atr = A[w,v] = x1w.x2[:,v]
#define DOT_AB(vv) \
  float a = 0.f, atr = 0.f; \
  { const uint4* q1 = (const uint4*)(x1s + (vv)*CC); \
    const uint4* q2 = (const uint4*)(x2s + (vv)*CC); \
    _Pragma("unroll") \
    for (int j = 0; j < 4; ++j) { \
      uint4 u1 = q1[j], u2 = q2[j]; \
      D2(u1.x, x2w, 8*j+0, a) D2(u1.y, x2w, 8*j+2, a) \
      D2(u1.z, x2w, 8*j+4, a) D2(u1.w, x2w, 8*j+6, a) \
      D2(u2.x, x1w, 8*j+0, atr) D2(u2.y, x1w, 8*j+2, atr) \
      D2(u2.z, x1w, 8*j+4, atr) D2(u2.w, x1w, 8*j+6, atr) \
    } }

__global__ __launch_bounds__(TT, 2) void dymix(
    const float* __restrict__ x,
    const float* __restrict__ w1, const float* __restrict__ b1,
    const float* __restrict__ w2, const float* __restrict__ b2,
    const float* __restrict__ wm1, const float* __restrict__ bm1,
    const float* __restrict__ wm2, const float* __restrict__ bm2,
    float* __restrict__ out)
{
  // all [v][c] bf16, row = 64B
  __shared__ __align__(16) uint16_t Xs [VV*CC];
  __shared__ __align__(16) uint16_t x1s[VV*CC];
  __shared__ __align__(16) uint16_t x2s[VV*CC];
  __shared__ __align__(16) uint16_t h1s[VV*CC];
  __shared__ __align__(16) uint16_t g1s[VV*CC];
  __shared__ float rinv[VV];   // 1/rowsum
  __shared__ float cinv[VV];   // 1/colsum

  const int blk = blockIdx.x;
  const int n = blk / LL;
  const int l = blk - n*LL;
  const int t = threadIdx.x;
  const long xbase = (long)n*CC*VV*LL + l;

  // ---- Phase 0a: stage X (bf16) ----
  for (int i = t; i < VV*CC; i += TT) {
    int c = i / VV;
    int v = i - c*VV;
    Xs[v*CC + c] = (uint16_t)f2bf(x[xbase + (long)(c*VV + v)*LL]);
  }
  __syncthreads();

  // ---- Phase 0b: x1 = tanh(W1 X + b1), x2 = tanh(W2 X + b2) ----
  for (int i = t; i < VV*CC; i += TT) {
    int v = i >> 5, o = i & 31;
    float a1 = b1[o], a2 = b2[o];
    const uint32_t* rx = (const uint32_t*)(Xs + v*CC);
    #pragma unroll
    for (int j = 0; j < 16; ++j) {
      uint32_t u = rx[j];
      float f0 = bflo(u), f1 = bfhi(u);
      a1 += w1[o*CC + 2*j]*f0 + w1[o*CC + 2*j+1]*f1;
      a2 += w2[o*CC + 2*j]*f0 + w2[o*CC + 2*j+1]*f1;
    }
    x1s[v*CC + o] = (uint16_t)f2bf(tanhf(a1));
    x2s[v*CC + o] = (uint16_t)f2bf(tanhf(a2));
  }
  __syncthreads();

  const int w = t;
  const bool act = (w < VV);
  float x1w[CC], x2w[CC], hacc[CC], gacc[CC];

  // ---- Phase 1: softmax denominators (no cross-thread reduction needed) ----
  if (act) {
    const uint32_t* r1 = (const uint32_t*)(x1s + w*CC);
    const uint32_t* r2 = (const uint32_t*)(x2s + w*CC);
    #pragma unroll
    for (int j = 0; j < 16; ++j) {
      uint32_t u1 = r1[j], u2 = r2[j];
      x1w[2*j] = bflo(u1); x1w[2*j+1] = bfhi(u1);
      x2w[2*j] = bflo(u2); x2w[2*j+1] = bfhi(u2);
    }
    float rs = 0.f, cs = 0.f;
    for (int v = 0; v < VV; ++v) {
      DOT_AB(v)
      cs += __expf(a);     // colsum[w] = sum_v exp(A[v,w])
      rs += __expf(atr);   // rowsum[w] = sum_v exp(A[w,v])
    }
    rinv[w] = 1.f / rs;
    cinv[w] = 1.f / cs;
  }
  __syncthreads();

  // ---- Phase 2: diffusion step 1 (both adjacencies) ----
  if (act) {
    #pragma unroll
    for (int c = 0; c < CC; ++c) { hacc[c] = 0.f; gacc[c] = 0.f; }
    for (int v = 0; v < VV; ++v) {
      DOT_AB(v)
      float p0 = __expf(a)   * rinv[v];   // adj0[v,w]
      float p1 = __expf(atr) * cinv[v];   // adj1[v,w]
      const uint4* qx = (const uint4*)(Xs + v*CC);
      #pragma unroll
      for (int j = 0; j < 4; ++j) {
        uint4 u = qx[j];
        A2(u.x, 8*j+0, p0, hacc) A2(u.x, 8*j+0, p1, gacc)
        A2(u.y, 8*j+2, p0, hacc) A2(u.y, 8*j+2, p1, gacc)
        A2(u.z, 8*j+4, p0, hacc) A2(u.z, 8*j+4, p1, gacc)
        A2(u.w, 8*j+6, p0, hacc) A2(u.w, 8*j+6, p1, gacc)
      }
    }
    // h1 = AL*X + OM*hacc ; g1 = AL*X + OM*gacc ; store bf16
    const uint32_t* rxw = (const uint32_t*)(Xs + w*CC);
    uint32_t* ph = (uint32_t*)(h1s + w*CC);
    uint32_t* pg = (uint32_t*)(g1s + w*CC);
    #pragma unroll
    for (int j = 0; j < 16; ++j) {
      uint32_t u = rxw[j];
      float xe = bflo(u), xo = bfhi(u);
      float hv0 = AL*xe + OM*hacc[2*j], hv1 = AL*xo + OM*hacc[2*j+1];
      float gv0 = AL*xe + OM*gacc[2*j], gv1 = AL*xo + OM*gacc[2*j+1];
      ph[j] = f2bf(hv0) | (f2bf(hv1) << 16);
      pg[j] = f2bf(gv0) | (f2bf(gv1) << 16);
    }
  }
  __syncthreads();

  // ---- Phase 3: diffusion step 2 ----
  if (act) {
    #pragma unroll
    for (int c = 0; c < CC; ++c) { hacc[c] = 0.f; gacc[c] = 0.f; }
    for (int v = 0; v < VV; ++v) {
      DOT_AB(v)
      float p0 = __expf(a)   * rinv[v];
      float p1 = __expf(atr) * cinv[v];
      const uint4* qh = (const uint4*)(h1s + v*CC);
      const uint4* qg = (const uint4*)(g1s + v*CC);
      #pragma unroll
      for (int j = 0; j < 4; ++j) {
        uint4 uh = qh[j], ug = qg[j];
        A2(uh.x, 8*j+0, p0, hacc) A2(ug.x, 8*j+0, p1, gacc)
        A2(uh.y, 8*j+2, p0, hacc) A2(ug.y, 8*j+2, p1, gacc)
        A2(uh.z, 8*j+4, p0, hacc) A2(ug.z, 8*j+4, p1, gacc)
        A2(uh.w, 8*j+6, p0, hacc) A2(ug.w, 8*j+6, p1, gacc)
      }
    }
    // h2/g2 = AL*X + OM*acc (kept in hacc/gacc)
    #pragma unroll
    for (int c = 0; c < CC; ++c) {
      float xv = bf2f(Xs[w*CC + c]);
      hacc[c] = AL*xv + OM*hacc[c];
      gacc[c] = AL*xv + OM*gacc[c];
    }
  }
  __syncthreads();   // everyone done reading x1s/x2s — safe to reuse

  // ---- Phase 4: stash h2/g2 in x1s/x2s (own row), then MLP output ----
  if (act) {
    uint32_t* p2h = (uint32_t*)(x1s + w*CC);
    uint32_t* p2g = (uint32_t*)(x2s + w*CC);
    #pragma unroll
    for (int j = 0; j < 16; ++j) {
      p2h[j] = f2bf(hacc[2*j]) | (f2bf(hacc[2*j+1]) << 16);
      p2g[j] = f2bf(gacc[2*j]) | (f2bf(gacc[2*j+1]) << 16);
    }
    float oacc[CC];
    #pragma unroll
    for (int o = 0; o < CC; ++o) oacc[o] = bm1[o] + bm2[o];
    for (int c = 0; c < CC; ++c) {           // runtime loop, values from LDS
      float xv  = bf2f(Xs [w*CC + c]);
      float h1v = bf2f(h1s[w*CC + c]);
      float g1v = bf2f(g1s[w*CC + c]);
      float h2v = bf2f(x1s[w*CC + c]);
      float g2v = bf2f(x2s[w*CC + c]);
      #pragma unroll
      for (int o = 0; o < CC; ++o) {
        oacc[o] += (wm1[o*96 + c] + wm2[o*96 + c]) * xv
                 +  wm1[o*96 + 32 + c] * h1v
                 +  wm2[o*96 + 32 + c] * g1v
                 +  wm1[o*96 + 64 + c] * h2v
                 +  wm2[o*96 + 64 + c] * g2v;
      }
    }
    const long obase = (long)n*CC*VV*LL + (long)w*LL + l;
    #pragma unroll
    for (int o = 0; o < CC; ++o)
      out[obase + (long)o*VV*LL] = oacc[o];
  }
}

extern "C" void kernel_launch(void* const* d_in, const int* in_sizes, int n_in,
                              void* d_out, int out_size, void* d_ws, size_t ws_size,
                              hipStream_t stream) {
  (void)in_sizes; (void)n_in; (void)out_size; (void)d_ws; (void)ws_size;
  dymix<<<dim3(NN*LL), dim3(TT), 0, stream>>>(
      (const float*)d_in[0],
      (const float*)d_in[1], (const float*)d_in[2],
      (const float*)d_in[3], (const float*)d_in[4],
      (const float*)d_in[5], (const float*)d_in[6],
      (const float*)d_in[7], (const float*)d_in[8],
      (float*)d_out);
}

// Round 3
// 612.862 us; speedup vs baseline: 3.3600x; 3.3600x over previous
//
#include <hip/hip_runtime.h>
#include <stdint.h>

#define TT 512
#define AL 0.05f
#define OM 0.95f

typedef short s8v __attribute__((ext_vector_type(8)));
typedef float f4v __attribute__((ext_vector_type(4)));
typedef float f16v __attribute__((ext_vector_type(16)));

#define MF32(a,b,c) __builtin_amdgcn_mfma_f32_32x32x16_bf16(a,b,c,0,0,0)
#define MF16(a,b,c) __builtin_amdgcn_mfma_f32_16x16x32_bf16(a,b,c,0,0,0)

__device__ __forceinline__ uint16_t f2bf(float f){ union{float f;uint32_t i;}t; t.f=f; return (uint16_t)((t.i + 0x7fffu + ((t.i>>16)&1u))>>16); }
__device__ __forceinline__ float bf2f(uint16_t h){ union{uint32_t i;float f;}t; t.i=((uint32_t)h)<<16; return t.f; }
__device__ __forceinline__ s8v ld8(const uint16_t* p){ return *(const s8v*)p; }

// LDS map (uint16 units):
//  x1s[12800]  [v][32]   : x1 (lin out)         ; MLP: XT  (X as [v][c])
//  x2s[12800]  [v][32]   : x2                   ; MLP: H1vc
//  Xcv[12800]  [c][400]  : X                    ; MLP: folded weights (5x[32][40]) + bias fp32[32]
//  Hcv[12800]  [c][400]  : H1                   ; MLP: H2' as [v][32]
//  Gcv[12800]  [c][400]  : G1                   ; MLP: G2' as [v][32]
//  Pb [16000]  [w][40]   : P slab (ONE chain at a time — chains serialized)
__global__ __launch_bounds__(TT,2) void dymix(
    const float* __restrict__ x,
    const float* __restrict__ w1, const float* __restrict__ b1,
    const float* __restrict__ w2, const float* __restrict__ b2,
    const float* __restrict__ wm1, const float* __restrict__ bm1,
    const float* __restrict__ wm2, const float* __restrict__ bm2,
    float* __restrict__ out)
{
  __shared__ __align__(16) uint16_t x1s[12800];
  __shared__ __align__(16) uint16_t x2s[12800];
  __shared__ __align__(16) uint16_t Xcv[12800];
  __shared__ __align__(16) uint16_t Hcv[12800];
  __shared__ __align__(16) uint16_t Gcv[12800];
  __shared__ __align__(16) uint16_t Pb[16000];
  __shared__ __align__(16) uint16_t rinvb[400];
  __shared__ __align__(16) uint16_t cinvb[400];

  const int blk = blockIdx.x;
  // group the 12 l-blocks of each n on one XCD (blk%8 heuristic; perf-only)
  const int xcd = blk & 7, slot = blk >> 3;
  const int n = xcd*4 + slot/12;
  const int l = slot - (slot/12)*12;
  const int t = threadIdx.x;
  const int wv = t >> 6;
  const int lane = t & 63;
  const int q  = lane >> 4;   // quad for 16x16
  const int r  = lane & 15;
  const int h2 = lane >> 5;   // half for 32x32
  const int m32 = lane & 31;
  const long xbase = (long)n*153600 + l;

  // ---------- Phase 0: stage X -> Xcv [c][400] ----------
  for (int i = t; i < 12800; i += TT) {
    Xcv[i] = f2bf(x[xbase + (long)i*12]);   // i == c*400+v
  }
  __syncthreads();

  // ---------- Phase L prep: XT (Pb[0..12800)) + stage lin weights ----------
  for (int i = t; i < 12800; i += TT) { int v = i>>5, c = i&31; Pb[i] = Xcv[c*400 + v]; }
  for (int i = t; i < 1024; i += TT) {
    int o = i>>5, c = i&31;
    Pb[12800 + o*40 + c] = f2bf(w1[i]);
    Pb[14080 + o*40 + c] = f2bf(w2[i]);
  }
  if (t < 32) { ((float*)(Pb+15360))[t] = b1[t]; ((float*)(Pb+15424))[t] = b2[t]; }
  __syncthreads();

  // ---------- Phase L: x1 = tanh(W1 X + b1), x2 = tanh(W2 X + b2) -> [v][32] ----------
  #pragma unroll
  for (int j = 0; j < 4; ++j) {
    int u = wv + 8*j;
    if (u < 24) {
      int nt = u >> 1, li = u & 1;
      const uint16_t* W = Pb + 12800 + li*1280;
      const float* bf = (const float*)(Pb + 15360 + li*64);
      uint16_t* dst = li ? x2s : x1s;
      f16v z = {};
      #pragma unroll
      for (int kk = 0; kk < 2; ++kk) {
        s8v a = ld8(W + m32*40 + kk*16 + h2*8);
        s8v b = ld8(Pb + (nt*32 + m32)*32 + kk*16 + h2*8);
        z = MF32(a, b, z);
      }
      int v = nt*32 + m32;
      #pragma unroll
      for (int g = 0; g < 4; ++g) {
        union{uint16_t u4[4]; uint2 d;} pk;
        #pragma unroll
        for (int e = 0; e < 4; ++e) { int cc = 8*g + 4*h2 + e; pk.u4[e] = f2bf(tanhf(z[4*g+e] + bf[cc])); }
        *(uint2*)(dst + v*32 + 8*g + 4*h2) = pk.d;
      }
    } else if (u < 28) {
      int li = (u-24)>>1, mt = u&1;
      const uint16_t* W = Pb + 12800 + li*1280;
      const float* bf = (const float*)(Pb + 15360 + li*64);
      uint16_t* dst = li ? x2s : x1s;
      s8v a = ld8(W + (mt*16 + r)*40 + q*8);
      s8v b = ld8(Pb + (384 + r)*32 + q*8);
      f4v z4 = {}; z4 = MF16(a, b, z4);
      union{uint16_t u4[4]; uint2 d;} pk;
      #pragma unroll
      for (int e = 0; e < 4; ++e) { int cc = mt*16 + q*4 + e; pk.u4[e] = f2bf(tanhf(z4[e] + bf[cc])); }
      *(uint2*)(dst + (384 + r)*32 + mt*16 + q*4) = pk.d;
    }
  }
  __syncthreads();

  // ---------- Stats: rowsum/colsum of exp(A) ----------
  float* rsf = (float*)Pb;          // [400]
  float* csf = ((float*)Pb) + 400;  // [400]
  for (int i = t; i < 400; i += TT) csf[i] = 0.f;
  __syncthreads();
  {
    s8v av[4]; f4v rac[4] = {{},{},{},{}};
    #pragma unroll
    for (int jj = 0; jj < 4; ++jj) { int vt = wv + 8*jj; if (vt < 25) av[jj] = ld8(x1s + (vt*16 + r)*32 + q*8); }
    for (int wt = 0; wt < 25; ++wt) {
      s8v b = ld8(x2s + (wt*16 + r)*32 + q*8);
      float cp = 0.f;
      #pragma unroll
      for (int jj = 0; jj < 4; ++jj) {
        int vt = wv + 8*jj;
        if (vt < 25) {
          f4v z = {}; z = MF16(av[jj], b, z);
          #pragma unroll
          for (int e = 0; e < 4; ++e) { float ev = __expf(z[e]); rac[jj][e] += ev; cp += ev; }
        }
      }
      cp += __shfl_xor(cp, 16); cp += __shfl_xor(cp, 32);
      if (q == 0) atomicAdd(&csf[wt*16 + r], cp);
    }
    #pragma unroll
    for (int jj = 0; jj < 4; ++jj) {
      int vt = wv + 8*jj;
      if (vt < 25) {
        #pragma unroll
        for (int e = 0; e < 4; ++e) {
          float s = rac[jj][e];
          s += __shfl_xor(s,1); s += __shfl_xor(s,2); s += __shfl_xor(s,4); s += __shfl_xor(s,8);
          if (r == 0) rsf[vt*16 + q*4 + e] = s;
        }
      }
    }
  }
  __syncthreads();
  for (int i = t; i < 400; i += TT) { rinvb[i] = f2bf(1.f/rsf[i]); cinvb[i] = f2bf(1.f/csf[i]); }
  __syncthreads();

  // ---------- Diffusion steps (chains SERIALIZED per slab — Pb is single-chain) ----------
  f16v acc[4];   // j = chain*2 + jj ; task uu = wv + 8*jj
  for (int step = 0; step < 2; ++step) {
    { f16v zv = {}; acc[0]=zv; acc[1]=zv; acc[2]=zv; acc[3]=zv; }
    const uint16_t* AH = step ? Hcv : Xcv;
    const uint16_t* AG = step ? Gcv : Xcv;
    for (int sb = 0; sb < 13; ++sb) {
      const int vbase = sb*32;
      const bool lastsb = (sb == 12);
      for (int chain = 0; chain < 2; ++chain) {
        // ---- T phase: write P slab for THIS chain only ----
        if (!lastsb) {
          if (chain == 0) {
            s8v t0a0 = ld8(x1s + (vbase + m32)*32 + h2*8);
            s8v t0a1 = ld8(x1s + (vbase + m32)*32 + 16 + h2*8);
            float rv[16];
            #pragma unroll
            for (int e2 = 0; e2 < 16; ++e2) { int row = (e2&3) + 8*(e2>>2) + 4*h2; rv[e2] = bf2f(rinvb[vbase + row]); }
            #pragma unroll
            for (int jj = 0; jj < 2; ++jj) {
              int u = wv + 8*jj;
              if (u < 12) {             // full tile, cols w = u*32..
                s8v b0 = ld8(x2s + (u*32 + m32)*32 + h2*8);
                s8v b1 = ld8(x2s + (u*32 + m32)*32 + 16 + h2*8);
                f16v z = {}; z = MF32(t0a0, b0, z); z = MF32(t0a1, b1, z);
                uint16_t* pw = Pb + (u*32 + m32)*40;
                #pragma unroll
                for (int g = 0; g < 4; ++g) {
                  union{uint16_t u4[4]; uint2 d;} pk;
                  #pragma unroll
                  for (int e = 0; e < 4; ++e) pk.u4[e] = f2bf(__expf(z[4*g+e]) * rv[4*g+e]);
                  *(uint2*)(pw + 8*g + 4*h2) = pk.d;
                }
              } else if (u == 12) {     // tail cols w = 384..399
                #pragma unroll
                for (int mt = 0; mt < 2; ++mt) {
                  s8v a = ld8(x1s + (vbase + mt*16 + r)*32 + q*8);
                  s8v b = ld8(x2s + (384 + r)*32 + q*8);
                  f4v z4 = {}; z4 = MF16(a, b, z4);
                  union{uint16_t u4[4]; uint2 d;} pk;
                  #pragma unroll
                  for (int e = 0; e < 4; ++e) { int row = mt*16 + q*4 + e; pk.u4[e] = f2bf(__expf(z4[e]) * bf2f(rinvb[vbase+row])); }
                  *(uint2*)(Pb + (384 + r)*40 + mt*16 + q*4) = pk.d;
                }
              }
            }
          } else {
            s8v t1b0 = ld8(x2s + (vbase + m32)*32 + h2*8);
            s8v t1b1 = ld8(x2s + (vbase + m32)*32 + 16 + h2*8);
            float cv = bf2f(cinvb[vbase + m32]);
            #pragma unroll
            for (int jj = 0; jj < 2; ++jj) {
              int u = wv + 8*jj;
              if (u < 12) {             // full tile, rows w = u*32..
                s8v a0 = ld8(x1s + (u*32 + m32)*32 + h2*8);
                s8v a1 = ld8(x1s + (u*32 + m32)*32 + 16 + h2*8);
                f16v z = {}; z = MF32(a0, t1b0, z); z = MF32(a1, t1b1, z);
                #pragma unroll
                for (int e2 = 0; e2 < 16; ++e2) {
                  int w = u*32 + (e2&3) + 8*(e2>>2) + 4*h2;
                  Pb[w*40 + m32] = f2bf(__expf(z[e2]) * cv);
                }
              } else if (u == 12) {     // tail rows w = 384..399
                #pragma unroll
                for (int ct = 0; ct < 2; ++ct) {
                  s8v a = ld8(x1s + (384 + r)*32 + q*8);
                  s8v b = ld8(x2s + (vbase + ct*16 + r)*32 + q*8);
                  f4v z4 = {}; z4 = MF16(a, b, z4);
                  float cvt = bf2f(cinvb[vbase + ct*16 + r]);
                  #pragma unroll
                  for (int e = 0; e < 4; ++e) Pb[(384 + q*4 + e)*40 + ct*16 + r] = f2bf(__expf(z4[e]) * cvt);
                }
              }
            }
          }
        } else {
          // sb==12: K=16 slab, 16x16 tiles only.
          if (chain == 0) {
            for (int i = t; i < 3200; i += TT) {         // zero P[*][16..31] once
              int w = i >> 3;
              ((uint32_t*)(Pb + w*40 + 16))[i & 7] = 0u;
            }
            s8v t0a = ld8(x1s + (384 + r)*32 + q*8);
            #pragma unroll
            for (int jj = 0; jj < 4; ++jj) {
              int u = wv + 8*jj;
              if (u < 25) {             // cols w = u*16..
                s8v b = ld8(x2s + (u*16 + r)*32 + q*8);
                f4v z4 = {}; z4 = MF16(t0a, b, z4);
                union{uint16_t u4[4]; uint2 d;} pk;
                #pragma unroll
                for (int e = 0; e < 4; ++e) pk.u4[e] = f2bf(__expf(z4[e]) * bf2f(rinvb[384 + q*4 + e]));
                *(uint2*)(Pb + (u*16 + r)*40 + q*4) = pk.d;
              }
            }
          } else {
            s8v t1b = ld8(x2s + (384 + r)*32 + q*8);
            float cvt = bf2f(cinvb[384 + r]);
            #pragma unroll
            for (int jj = 0; jj < 4; ++jj) {
              int u = wv + 8*jj;
              if (u < 25) {             // rows w = u*16..
                s8v a = ld8(x1s + (u*16 + r)*32 + q*8);
                f4v z4 = {}; z4 = MF16(a, t1b, z4);
                #pragma unroll
                for (int e = 0; e < 4; ++e) Pb[(u*16 + q*4 + e)*40 + r] = f2bf(__expf(z4[e]) * cvt);
              }
            }
          }
        }
        __syncthreads();
        // ---- GEMM phase: acc += Hold . P (this chain) ----
        {
          const uint16_t* Acv = chain ? AG : AH;
          #pragma unroll
          for (int jj = 0; jj < 2; ++jj) {
            int uu = wv + 8*jj;
            int j = chain*2 + jj;
            if (uu < 12) {
              int kmax = lastsb ? 1 : 2;
              for (int kk = 0; kk < kmax; ++kk) {
                s8v a = ld8(Acv + m32*400 + vbase + kk*16 + h2*8);
                s8v b = ld8(Pb + (uu*32 + m32)*40 + kk*16 + h2*8);
                acc[j] = MF32(a, b, acc[j]);
              }
            } else if (uu < 14) {
              int mt = uu - 12;
              int koff = (lastsb && q >= 2) ? 0 : q*8;   // q>=2 k-range is zeroed in P; avoid cross-row garbage read
              s8v a = ld8(Acv + (mt*16 + r)*400 + vbase + koff);
              s8v b = ld8(Pb + (384 + r)*40 + q*8);
              f4v c4 = { acc[j][0], acc[j][1], acc[j][2], acc[j][3] };
              c4 = MF16(a, b, c4);
              acc[j][0]=c4[0]; acc[j][1]=c4[1]; acc[j][2]=c4[2]; acc[j][3]=c4[3];
            }
          }
        }
        __syncthreads();
      } // chain loop
    } // slab loop
    // ---- step-1 epilogue: H1/G1 = a*X + (1-a)*acc -> Hcv/Gcv [c][400] ----
    if (step == 0) {
      #pragma unroll
      for (int j = 0; j < 4; ++j) {
        int chain = j >> 1;
        int uu = wv + 8*(j & 1);
        if (uu < 14) {
          uint16_t* dst = chain ? Gcv : Hcv;
          if (uu < 12) {
            int w = uu*32 + m32;
            #pragma unroll
            for (int e2 = 0; e2 < 16; ++e2) {
              int c = (e2&3) + 8*(e2>>2) + 4*h2;
              float xv = bf2f(Xcv[c*400 + w]);
              dst[c*400 + w] = f2bf(AL*xv + OM*acc[j][e2]);
            }
          } else {
            int mt = uu - 12; int w = 384 + r;
            #pragma unroll
            for (int e = 0; e < 4; ++e) {
              int c = mt*16 + q*4 + e;
              float xv = bf2f(Xcv[c*400 + w]);
              dst[c*400 + w] = f2bf(AL*xv + OM*acc[j][e]);
            }
          }
        }
      }
    }
  } // step loop

  // ---------- MLP prep 1: transposes into [v][32] ----------
  for (int i = t; i < 12800; i += TT) {
    int v = i >> 5, c = i & 31;
    x1s[i] = Xcv[c*400 + v];   // XT
    x2s[i] = Hcv[c*400 + v];   // H1vc
    Pb[i]  = Gcv[c*400 + v];   // G1vc
  }
  __syncthreads();
  // ---------- MLP prep 2: folded weights + H2'/G2' ----------
  for (int i = t; i < 1024; i += TT) {
    int o = i >> 5, c = i & 31;
    float h2w = wm1[o*96 + 64 + c], g2w = wm2[o*96 + 64 + c];
    Xcv[o*40 + c]        = f2bf(wm1[o*96 + c] + wm2[o*96 + c] + AL*(h2w + g2w));
    Xcv[1280 + o*40 + c] = f2bf(wm1[o*96 + 32 + c]);   // H1 weights
    Xcv[2560 + o*40 + c] = f2bf(h2w);                  // H2' weights
    Xcv[3840 + o*40 + c] = f2bf(wm2[o*96 + 32 + c]);   // G1 weights
    Xcv[5120 + o*40 + c] = f2bf(g2w);                  // G2' weights
  }
  if (t < 32) ((float*)(Xcv + 6400))[t] = bm1[t] + bm2[t];
  #pragma unroll
  for (int j = 0; j < 4; ++j) {
    int chain = j >> 1;
    int uu = wv + 8*(j & 1);
    if (uu < 14) {
      uint16_t* dst = chain ? Gcv : Hcv;   // reused as [v][32]
      if (uu < 12) {
        int w = uu*32 + m32;
        #pragma unroll
        for (int g = 0; g < 4; ++g) {
          union{uint16_t u4[4]; uint2 d;} pk;
          #pragma unroll
          for (int e = 0; e < 4; ++e) pk.u4[e] = f2bf(OM*acc[j][4*g+e]);
          *(uint2*)(dst + w*32 + 8*g + 4*h2) = pk.d;
        }
      } else {
        int mt = uu - 12; int w = 384 + r;
        union{uint16_t u4[4]; uint2 d;} pk;
        #pragma unroll
        for (int e = 0; e < 4; ++e) pk.u4[e] = f2bf(OM*acc[j][e]);
        *(uint2*)(dst + w*32 + mt*16 + q*4) = pk.d;
      }
    }
  }
  __syncthreads();

  // ---------- MLP: out[o,v] = sum_p W_p . feat_p + bias ----------
  {
    const uint16_t* feats[5] = { x1s, x2s, Hcv, Pb, Gcv };  // X, H1, H2', G1, G2'
    const float* boF = (const float*)(Xcv + 6400);
    const long obase = (long)n*153600 + l;
    #pragma unroll
    for (int j = 0; j < 2; ++j) {
      int u = wv + 8*j;
      if (u < 12) {
        int nt = u;
        f16v z = {};
        #pragma unroll
        for (int p = 0; p < 5; ++p) {
          #pragma unroll
          for (int kk = 0; kk < 2; ++kk) {
            s8v a = ld8(Xcv + p*1280 + m32*40 + kk*16 + h2*8);
            s8v b = ld8(feats[p] + (nt*32 + m32)*32 + kk*16 + h2*8);
            z = MF32(a, b, z);
          }
        }
        int v = nt*32 + m32;
        #pragma unroll
        for (int e2 = 0; e2 < 16; ++e2) {
          int o = (e2&3) + 8*(e2>>2) + 4*h2;
          out[obase + (long)o*4800 + (long)v*12] = z[e2] + boF[o];
        }
      } else if (u < 14) {
        int mt = u - 12;
        f4v z4 = {};
        #pragma unroll
        for (int p = 0; p < 5; ++p) {
          s8v a = ld8(Xcv + p*1280 + (mt*16 + r)*40 + q*8);
          s8v b = ld8(feats[p] + (384 + r)*32 + q*8);
          z4 = MF16(a, b, z4);
        }
        int v = 384 + r;
        #pragma unroll
        for (int e = 0; e < 4; ++e) {
          int o = mt*16 + q*4 + e;
          out[obase + (long)o*4800 + (long)v*12] = z4[e] + boF[o];
        }
      }
    }
  }
}

extern "C" void kernel_launch(void* const* d_in, const int* in_sizes, int n_in,
                              void* d_out, int out_size, void* d_ws, size_t ws_size,
                              hipStream_t stream) {
  (void)in_sizes; (void)n_in; (void)out_size; (void)d_ws; (void)ws_size;
  dymix<<<dim3(384), dim3(TT), 0, stream>>>(
      (const float*)d_in[0],
      (const float*)d_in[1], (const float*)d_in[2],
      (const float*)d_in[3], (const float*)d_in[4],
      (const float*)d_in[5], (const float*)d_in[6],
      (const float*)d_in[7], (const float*)d_in[8],
      (float*)d_out);
}

// Round 4
// 608.203 us; speedup vs baseline: 3.3857x; 1.0077x over previous
//
#include <hip/hip_runtime.h>
#include <stdint.h>

#define TT 512
#define AL 0.05f
#define OM 0.95f

typedef short s8v __attribute__((ext_vector_type(8)));
typedef float f4v __attribute__((ext_vector_type(4)));
typedef float f16v __attribute__((ext_vector_type(16)));

#define MF32(a,b,c) __builtin_amdgcn_mfma_f32_32x32x16_bf16(a,b,c,0,0,0)
#define MF16(a,b,c) __builtin_amdgcn_mfma_f32_16x16x32_bf16(a,b,c,0,0,0)

__device__ __forceinline__ uint16_t f2bf(float f){ union{float f;uint32_t i;}t; t.f=f; return (uint16_t)((t.i + 0x7fffu + ((t.i>>16)&1u))>>16); }
__device__ __forceinline__ float bf2f(uint16_t h){ union{uint32_t i;float f;}t; t.i=((uint32_t)h)<<16; return t.f; }
__device__ __forceinline__ s8v ld8(const uint16_t* p){ return *(const s8v*)p; }

// ---------- pre: x[n][c][v][l] -> xT[n][l][c][v] (both sides coalesced) ----------
__global__ __launch_bounds__(256) void pre_t(const float* __restrict__ x, float* __restrict__ xT){
  int idx = blockIdx.x*256 + threadIdx.x;      // n*12800 + cv, 409600 total
  int n = idx / 12800, cv = idx - n*12800;
  const float4* src = (const float4*)(x + (long)idx*12);
  float4 a = src[0], b = src[1], c = src[2];
  float vals[12] = {a.x,a.y,a.z,a.w,b.x,b.y,b.z,b.w,c.x,c.y,c.z,c.w};
  long base = (long)n*153600 + cv;
  #pragma unroll
  for (int l = 0; l < 12; ++l) xT[base + (long)l*12800] = vals[l];
}

// ---------- post: oS[n][l][o][v] -> out[n][o][v][l] (both sides coalesced) ----------
__global__ __launch_bounds__(256) void post_t(const float* __restrict__ oS, float* __restrict__ out){
  int idx = blockIdx.x*256 + threadIdx.x;      // n*12800 + o*400 + v
  int n = idx / 12800, ov = idx - n*12800;
  long base = (long)n*153600 + ov;
  float vals[12];
  #pragma unroll
  for (int l = 0; l < 12; ++l) vals[l] = oS[base + (long)l*12800];
  float4* dst = (float4*)(out + (long)idx*12);
  dst[0] = make_float4(vals[0],vals[1],vals[2],vals[3]);
  dst[1] = make_float4(vals[4],vals[5],vals[6],vals[7]);
  dst[2] = make_float4(vals[8],vals[9],vals[10],vals[11]);
}

// LDS map (uint16 units):
//  x1s[12800]  [v][32]   : x1 (lin out)         ; MLP: XT  (X as [v][c])
//  x2s[12800]  [v][32]   : x2                   ; MLP: H1vc
//  Xcv[12800]  [c][400]  : X                    ; MLP: folded weights (5x[32][40]) + bias fp32[32]
//  Hcv[12800]  [c][400]  : H1                   ; MLP: H2' as [v][32]
//  Gcv[12800]  [c][400]  : G1                   ; MLP: G2' as [v][32]
//  Pb [16000]  [w][40]   : P slab (ONE chain at a time — chains serialized)
__global__ __launch_bounds__(TT,2) void dymix(
    const float* __restrict__ x,
    const float* __restrict__ w1, const float* __restrict__ b1,
    const float* __restrict__ w2, const float* __restrict__ b2,
    const float* __restrict__ wm1, const float* __restrict__ bm1,
    const float* __restrict__ wm2, const float* __restrict__ bm2,
    float* __restrict__ out,
    const float* __restrict__ xT, float* __restrict__ outS, int staged)
{
  __shared__ __align__(16) uint16_t x1s[12800];
  __shared__ __align__(16) uint16_t x2s[12800];
  __shared__ __align__(16) uint16_t Xcv[12800];
  __shared__ __align__(16) uint16_t Hcv[12800];
  __shared__ __align__(16) uint16_t Gcv[12800];
  __shared__ __align__(16) uint16_t Pb[16000];
  __shared__ __align__(16) uint16_t rinvb[400];
  __shared__ __align__(16) uint16_t cinvb[400];

  const int blk = blockIdx.x;
  // group the 12 l-blocks of each n on one XCD (blk%8 heuristic; perf-only)
  const int xcd = blk & 7, slot = blk >> 3;
  const int n = xcd*4 + slot/12;
  const int l = slot - (slot/12)*12;
  const int t = threadIdx.x;
  const int wv = t >> 6;
  const int lane = t & 63;
  const int q  = lane >> 4;   // quad for 16x16
  const int r  = lane & 15;
  const int h2 = lane >> 5;   // half for 32x32
  const int m32 = lane & 31;
  const long xbase = (long)n*153600 + l;
  const long sbase = (long)(n*12 + l)*12800;   // staged slice base

  // ---------- Phase 0: stage X -> Xcv [c][400] ----------
  if (staged) {
    const float4* xs4 = (const float4*)(xT + sbase);
    for (int i = t; i < 3200; i += TT) {
      float4 vv = xs4[i];
      uint2 pk;
      pk.x = (uint32_t)f2bf(vv.x) | ((uint32_t)f2bf(vv.y) << 16);
      pk.y = (uint32_t)f2bf(vv.z) | ((uint32_t)f2bf(vv.w) << 16);
      *(uint2*)(Xcv + 4*i) = pk;
    }
  } else {
    for (int i = t; i < 12800; i += TT) {
      Xcv[i] = f2bf(x[xbase + (long)i*12]);   // i == c*400+v
    }
  }
  __syncthreads();

  // ---------- Phase L prep: XT (Pb[0..12800)) + stage lin weights ----------
  for (int i = t; i < 12800; i += TT) { int v = i>>5, c = i&31; Pb[i] = Xcv[c*400 + v]; }
  for (int i = t; i < 1024; i += TT) {
    int o = i>>5, c = i&31;
    Pb[12800 + o*40 + c] = f2bf(w1[i]);
    Pb[14080 + o*40 + c] = f2bf(w2[i]);
  }
  if (t < 32) { ((float*)(Pb+15360))[t] = b1[t]; ((float*)(Pb+15424))[t] = b2[t]; }
  __syncthreads();

  // ---------- Phase L: x1 = tanh(W1 X + b1), x2 = tanh(W2 X + b2) -> [v][32] ----------
  #pragma unroll
  for (int j = 0; j < 4; ++j) {
    int u = wv + 8*j;
    if (u < 24) {
      int nt = u >> 1, li = u & 1;
      const uint16_t* W = Pb + 12800 + li*1280;
      const float* bf = (const float*)(Pb + 15360 + li*64);
      uint16_t* dst = li ? x2s : x1s;
      f16v z = {};
      #pragma unroll
      for (int kk = 0; kk < 2; ++kk) {
        s8v a = ld8(W + m32*40 + kk*16 + h2*8);
        s8v b = ld8(Pb + (nt*32 + m32)*32 + kk*16 + h2*8);
        z = MF32(a, b, z);
      }
      int v = nt*32 + m32;
      #pragma unroll
      for (int g = 0; g < 4; ++g) {
        union{uint16_t u4[4]; uint2 d;} pk;
        #pragma unroll
        for (int e = 0; e < 4; ++e) { int cc = 8*g + 4*h2 + e; pk.u4[e] = f2bf(tanhf(z[4*g+e] + bf[cc])); }
        *(uint2*)(dst + v*32 + 8*g + 4*h2) = pk.d;
      }
    } else if (u < 28) {
      int li = (u-24)>>1, mt = u&1;
      const uint16_t* W = Pb + 12800 + li*1280;
      const float* bf = (const float*)(Pb + 15360 + li*64);
      uint16_t* dst = li ? x2s : x1s;
      s8v a = ld8(W + (mt*16 + r)*40 + q*8);
      s8v b = ld8(Pb + (384 + r)*32 + q*8);
      f4v z4 = {}; z4 = MF16(a, b, z4);
      union{uint16_t u4[4]; uint2 d;} pk;
      #pragma unroll
      for (int e = 0; e < 4; ++e) { int cc = mt*16 + q*4 + e; pk.u4[e] = f2bf(tanhf(z4[e] + bf[cc])); }
      *(uint2*)(dst + (384 + r)*32 + mt*16 + q*4) = pk.d;
    }
  }
  __syncthreads();

  // ---------- Stats: rowsum/colsum of exp(A) ----------
  float* rsf = (float*)Pb;          // [400]
  float* csf = ((float*)Pb) + 400;  // [400]
  for (int i = t; i < 400; i += TT) csf[i] = 0.f;
  __syncthreads();
  {
    s8v av[4]; f4v rac[4] = {{},{},{},{}};
    #pragma unroll
    for (int jj = 0; jj < 4; ++jj) { int vt = wv + 8*jj; if (vt < 25) av[jj] = ld8(x1s + (vt*16 + r)*32 + q*8); }
    for (int wt = 0; wt < 25; ++wt) {
      s8v b = ld8(x2s + (wt*16 + r)*32 + q*8);
      float cp = 0.f;
      #pragma unroll
      for (int jj = 0; jj < 4; ++jj) {
        int vt = wv + 8*jj;
        if (vt < 25) {
          f4v z = {}; z = MF16(av[jj], b, z);
          #pragma unroll
          for (int e = 0; e < 4; ++e) { float ev = __expf(z[e]); rac[jj][e] += ev; cp += ev; }
        }
      }
      cp += __shfl_xor(cp, 16); cp += __shfl_xor(cp, 32);
      if (q == 0) atomicAdd(&csf[wt*16 + r], cp);
    }
    #pragma unroll
    for (int jj = 0; jj < 4; ++jj) {
      int vt = wv + 8*jj;
      if (vt < 25) {
        #pragma unroll
        for (int e = 0; e < 4; ++e) {
          float s = rac[jj][e];
          s += __shfl_xor(s,1); s += __shfl_xor(s,2); s += __shfl_xor(s,4); s += __shfl_xor(s,8);
          if (r == 0) rsf[vt*16 + q*4 + e] = s;
        }
      }
    }
  }
  __syncthreads();
  for (int i = t; i < 400; i += TT) { rinvb[i] = f2bf(1.f/rsf[i]); cinvb[i] = f2bf(1.f/csf[i]); }
  __syncthreads();

  // ---------- Diffusion steps (chains SERIALIZED per slab — Pb is single-chain) ----------
  f16v acc[4];   // j = chain*2 + jj ; task uu = wv + 8*jj
  for (int step = 0; step < 2; ++step) {
    { f16v zv = {}; acc[0]=zv; acc[1]=zv; acc[2]=zv; acc[3]=zv; }
    const uint16_t* AH = step ? Hcv : Xcv;
    const uint16_t* AG = step ? Gcv : Xcv;
    for (int sb = 0; sb < 13; ++sb) {
      const int vbase = sb*32;
      const bool lastsb = (sb == 12);
      for (int chain = 0; chain < 2; ++chain) {
        // ---- T phase: write P slab for THIS chain only ----
        if (!lastsb) {
          if (chain == 0) {
            s8v t0a0 = ld8(x1s + (vbase + m32)*32 + h2*8);
            s8v t0a1 = ld8(x1s + (vbase + m32)*32 + 16 + h2*8);
            float rv[16];
            #pragma unroll
            for (int e2 = 0; e2 < 16; ++e2) { int row = (e2&3) + 8*(e2>>2) + 4*h2; rv[e2] = bf2f(rinvb[vbase + row]); }
            #pragma unroll
            for (int jj = 0; jj < 2; ++jj) {
              int u = wv + 8*jj;
              if (u < 12) {             // full tile, cols w = u*32..
                s8v b0 = ld8(x2s + (u*32 + m32)*32 + h2*8);
                s8v b1 = ld8(x2s + (u*32 + m32)*32 + 16 + h2*8);
                f16v z = {}; z = MF32(t0a0, b0, z); z = MF32(t0a1, b1, z);
                uint16_t* pw = Pb + (u*32 + m32)*40;
                #pragma unroll
                for (int g = 0; g < 4; ++g) {
                  union{uint16_t u4[4]; uint2 d;} pk;
                  #pragma unroll
                  for (int e = 0; e < 4; ++e) pk.u4[e] = f2bf(__expf(z[4*g+e]) * rv[4*g+e]);
                  *(uint2*)(pw + 8*g + 4*h2) = pk.d;
                }
              } else if (u == 12) {     // tail cols w = 384..399
                #pragma unroll
                for (int mt = 0; mt < 2; ++mt) {
                  s8v a = ld8(x1s + (vbase + mt*16 + r)*32 + q*8);
                  s8v b = ld8(x2s + (384 + r)*32 + q*8);
                  f4v z4 = {}; z4 = MF16(a, b, z4);
                  union{uint16_t u4[4]; uint2 d;} pk;
                  #pragma unroll
                  for (int e = 0; e < 4; ++e) { int row = mt*16 + q*4 + e; pk.u4[e] = f2bf(__expf(z4[e]) * bf2f(rinvb[vbase+row])); }
                  *(uint2*)(Pb + (384 + r)*40 + mt*16 + q*4) = pk.d;
                }
              }
            }
          } else {
            s8v t1b0 = ld8(x2s + (vbase + m32)*32 + h2*8);
            s8v t1b1 = ld8(x2s + (vbase + m32)*32 + 16 + h2*8);
            float cv = bf2f(cinvb[vbase + m32]);
            #pragma unroll
            for (int jj = 0; jj < 2; ++jj) {
              int u = wv + 8*jj;
              if (u < 12) {             // full tile, rows w = u*32..
                s8v a0 = ld8(x1s + (u*32 + m32)*32 + h2*8);
                s8v a1 = ld8(x1s + (u*32 + m32)*32 + 16 + h2*8);
                f16v z = {}; z = MF32(a0, t1b0, z); z = MF32(a1, t1b1, z);
                #pragma unroll
                for (int e2 = 0; e2 < 16; ++e2) {
                  int w = u*32 + (e2&3) + 8*(e2>>2) + 4*h2;
                  Pb[w*40 + m32] = f2bf(__expf(z[e2]) * cv);
                }
              } else if (u == 12) {     // tail rows w = 384..399
                #pragma unroll
                for (int ct = 0; ct < 2; ++ct) {
                  s8v a = ld8(x1s + (384 + r)*32 + q*8);
                  s8v b = ld8(x2s + (vbase + ct*16 + r)*32 + q*8);
                  f4v z4 = {}; z4 = MF16(a, b, z4);
                  float cvt = bf2f(cinvb[vbase + ct*16 + r]);
                  #pragma unroll
                  for (int e = 0; e < 4; ++e) Pb[(384 + q*4 + e)*40 + ct*16 + r] = f2bf(__expf(z4[e]) * cvt);
                }
              }
            }
          }
        } else {
          // sb==12: K=16 slab, 16x16 tiles only.
          if (chain == 0) {
            for (int i = t; i < 3200; i += TT) {         // zero P[*][16..31] once
              int w = i >> 3;
              ((uint32_t*)(Pb + w*40 + 16))[i & 7] = 0u;
            }
            s8v t0a = ld8(x1s + (384 + r)*32 + q*8);
            #pragma unroll
            for (int jj = 0; jj < 4; ++jj) {
              int u = wv + 8*jj;
              if (u < 25) {             // cols w = u*16..
                s8v b = ld8(x2s + (u*16 + r)*32 + q*8);
                f4v z4 = {}; z4 = MF16(t0a, b, z4);
                union{uint16_t u4[4]; uint2 d;} pk;
                #pragma unroll
                for (int e = 0; e < 4; ++e) pk.u4[e] = f2bf(__expf(z4[e]) * bf2f(rinvb[384 + q*4 + e]));
                *(uint2*)(Pb + (u*16 + r)*40 + q*4) = pk.d;
              }
            }
          } else {
            s8v t1b = ld8(x2s + (384 + r)*32 + q*8);
            float cvt = bf2f(cinvb[384 + r]);
            #pragma unroll
            for (int jj = 0; jj < 4; ++jj) {
              int u = wv + 8*jj;
              if (u < 25) {             // rows w = u*16..
                s8v a = ld8(x1s + (u*16 + r)*32 + q*8);
                f4v z4 = {}; z4 = MF16(a, t1b, z4);
                #pragma unroll
                for (int e = 0; e < 4; ++e) Pb[(u*16 + q*4 + e)*40 + r] = f2bf(__expf(z4[e]) * cvt);
              }
            }
          }
        }
        __syncthreads();
        // ---- GEMM phase: acc += Hold . P (this chain) ----
        {
          const uint16_t* Acv = chain ? AG : AH;
          #pragma unroll
          for (int jj = 0; jj < 2; ++jj) {
            int uu = wv + 8*jj;
            int j = chain*2 + jj;
            if (uu < 12) {
              int kmax = lastsb ? 1 : 2;
              for (int kk = 0; kk < kmax; ++kk) {
                s8v a = ld8(Acv + m32*400 + vbase + kk*16 + h2*8);
                s8v b = ld8(Pb + (uu*32 + m32)*40 + kk*16 + h2*8);
                acc[j] = MF32(a, b, acc[j]);
              }
            } else if (uu < 14) {
              int mt = uu - 12;
              int koff = (lastsb && q >= 2) ? 0 : q*8;   // q>=2 k-range is zeroed in P; avoid cross-row garbage read
              s8v a = ld8(Acv + (mt*16 + r)*400 + vbase + koff);
              s8v b = ld8(Pb + (384 + r)*40 + q*8);
              f4v c4 = { acc[j][0], acc[j][1], acc[j][2], acc[j][3] };
              c4 = MF16(a, b, c4);
              acc[j][0]=c4[0]; acc[j][1]=c4[1]; acc[j][2]=c4[2]; acc[j][3]=c4[3];
            }
          }
        }
        __syncthreads();
      } // chain loop
    } // slab loop
    // ---- step-1 epilogue: H1/G1 = a*X + (1-a)*acc -> Hcv/Gcv [c][400] ----
    if (step == 0) {
      #pragma unroll
      for (int j = 0; j < 4; ++j) {
        int chain = j >> 1;
        int uu = wv + 8*(j & 1);
        if (uu < 14) {
          uint16_t* dst = chain ? Gcv : Hcv;
          if (uu < 12) {
            int w = uu*32 + m32;
            #pragma unroll
            for (int e2 = 0; e2 < 16; ++e2) {
              int c = (e2&3) + 8*(e2>>2) + 4*h2;
              float xv = bf2f(Xcv[c*400 + w]);
              dst[c*400 + w] = f2bf(AL*xv + OM*acc[j][e2]);
            }
          } else {
            int mt = uu - 12; int w = 384 + r;
            #pragma unroll
            for (int e = 0; e < 4; ++e) {
              int c = mt*16 + q*4 + e;
              float xv = bf2f(Xcv[c*400 + w]);
              dst[c*400 + w] = f2bf(AL*xv + OM*acc[j][e]);
            }
          }
        }
      }
    }
  } // step loop

  // ---------- MLP prep 1: transposes into [v][32] ----------
  for (int i = t; i < 12800; i += TT) {
    int v = i >> 5, c = i & 31;
    x1s[i] = Xcv[c*400 + v];   // XT
    x2s[i] = Hcv[c*400 + v];   // H1vc
    Pb[i]  = Gcv[c*400 + v];   // G1vc
  }
  __syncthreads();
  // ---------- MLP prep 2: folded weights + H2'/G2' ----------
  for (int i = t; i < 1024; i += TT) {
    int o = i >> 5, c = i & 31;
    float h2w = wm1[o*96 + 64 + c], g2w = wm2[o*96 + 64 + c];
    Xcv[o*40 + c]        = f2bf(wm1[o*96 + c] + wm2[o*96 + c] + AL*(h2w + g2w));
    Xcv[1280 + o*40 + c] = f2bf(wm1[o*96 + 32 + c]);   // H1 weights
    Xcv[2560 + o*40 + c] = f2bf(h2w);                  // H2' weights
    Xcv[3840 + o*40 + c] = f2bf(wm2[o*96 + 32 + c]);   // G1 weights
    Xcv[5120 + o*40 + c] = f2bf(g2w);                  // G2' weights
  }
  if (t < 32) ((float*)(Xcv + 6400))[t] = bm1[t] + bm2[t];
  #pragma unroll
  for (int j = 0; j < 4; ++j) {
    int chain = j >> 1;
    int uu = wv + 8*(j & 1);
    if (uu < 14) {
      uint16_t* dst = chain ? Gcv : Hcv;   // reused as [v][32]
      if (uu < 12) {
        int w = uu*32 + m32;
        #pragma unroll
        for (int g = 0; g < 4; ++g) {
          union{uint16_t u4[4]; uint2 d;} pk;
          #pragma unroll
          for (int e = 0; e < 4; ++e) pk.u4[e] = f2bf(OM*acc[j][4*g+e]);
          *(uint2*)(dst + w*32 + 8*g + 4*h2) = pk.d;
        }
      } else {
        int mt = uu - 12; int w = 384 + r;
        union{uint16_t u4[4]; uint2 d;} pk;
        #pragma unroll
        for (int e = 0; e < 4; ++e) pk.u4[e] = f2bf(OM*acc[j][e]);
        *(uint2*)(dst + w*32 + mt*16 + q*4) = pk.d;
      }
    }
  }
  __syncthreads();

  // ---------- MLP: out[o,v] = sum_p W_p . feat_p + bias ----------
  {
    const uint16_t* feats[5] = { x1s, x2s, Hcv, Pb, Gcv };  // X, H1, H2', G1, G2'
    const float* boF = (const float*)(Xcv + 6400);
    const long obase = (long)n*153600 + l;
    float* oSl = outS + sbase;
    #pragma unroll
    for (int j = 0; j < 2; ++j) {
      int u = wv + 8*j;
      if (u < 12) {
        int nt = u;
        f16v z = {};
        #pragma unroll
        for (int p = 0; p < 5; ++p) {
          #pragma unroll
          for (int kk = 0; kk < 2; ++kk) {
            s8v a = ld8(Xcv + p*1280 + m32*40 + kk*16 + h2*8);
            s8v b = ld8(feats[p] + (nt*32 + m32)*32 + kk*16 + h2*8);
            z = MF32(a, b, z);
          }
        }
        int v = nt*32 + m32;
        if (staged) {
          #pragma unroll
          for (int e2 = 0; e2 < 16; ++e2) {
            int o = (e2&3) + 8*(e2>>2) + 4*h2;
            oSl[o*400 + v] = z[e2] + boF[o];
          }
        } else {
          #pragma unroll
          for (int e2 = 0; e2 < 16; ++e2) {
            int o = (e2&3) + 8*(e2>>2) + 4*h2;
            out[obase + (long)o*4800 + (long)v*12] = z[e2] + boF[o];
          }
        }
      } else if (u < 14) {
        int mt = u - 12;
        f4v z4 = {};
        #pragma unroll
        for (int p = 0; p < 5; ++p) {
          s8v a = ld8(Xcv + p*1280 + (mt*16 + r)*40 + q*8);
          s8v b = ld8(feats[p] + (384 + r)*32 + q*8);
          z4 = MF16(a, b, z4);
        }
        int v = 384 + r;
        if (staged) {
          #pragma unroll
          for (int e = 0; e < 4; ++e) {
            int o = mt*16 + q*4 + e;
            oSl[o*400 + v] = z4[e] + boF[o];
          }
        } else {
          #pragma unroll
          for (int e = 0; e < 4; ++e) {
            int o = mt*16 + q*4 + e;
            out[obase + (long)o*4800 + (long)v*12] = z4[e] + boF[o];
          }
        }
      }
    }
  }
}

extern "C" void kernel_launch(void* const* d_in, const int* in_sizes, int n_in,
                              void* d_out, int out_size, void* d_ws, size_t ws_size,
                              hipStream_t stream) {
  (void)in_sizes; (void)n_in; (void)out_size;
  const size_t need = (size_t)32*12*12800*4;   // 19.66 MB staging slice (xT, reused as outS)
  const int staged = (ws_size >= need) ? 1 : 0;
  const float* x = (const float*)d_in[0];
  float* ws = (float*)d_ws;
  if (staged) pre_t<<<dim3(1600), dim3(256), 0, stream>>>(x, ws);
  dymix<<<dim3(384), dim3(TT), 0, stream>>>(
      x,
      (const float*)d_in[1], (const float*)d_in[2],
      (const float*)d_in[3], (const float*)d_in[4],
      (const float*)d_in[5], (const float*)d_in[6],
      (const float*)d_in[7], (const float*)d_in[8],
      (float*)d_out, ws, ws, staged);
  if (staged) post_t<<<dim3(1600), dim3(256), 0, stream>>>(ws, (float*)d_out);
}

// Round 5
// 412.886 us; speedup vs baseline: 4.9874x; 1.4731x over previous
//
#include <hip/hip_runtime.h>
#include <hip/hip_cooperative_groups.h>
#include <stdint.h>

namespace cg = cooperative_groups;

#define TT 512
#define AL 0.05f
#define OM 0.95f

typedef short s4v __attribute__((ext_vector_type(4)));
typedef short s8v __attribute__((ext_vector_type(8)));
typedef float f4v __attribute__((ext_vector_type(4)));
typedef float f16v __attribute__((ext_vector_type(16)));

#define MF32(a,b,c) __builtin_amdgcn_mfma_f32_32x32x16_bf16(a,b,c,0,0,0)
#define MF16(a,b,c) __builtin_amdgcn_mfma_f32_16x16x32_bf16(a,b,c,0,0,0)

__device__ __forceinline__ uint16_t f2bf(float f){ union{float f;uint32_t i;}t; t.f=f; return (uint16_t)((t.i + 0x7fffu + ((t.i>>16)&1u))>>16); }
__device__ __forceinline__ float bf2f(uint16_t h){ union{uint32_t i;float f;}t; t.i=((uint32_t)h)<<16; return t.f; }
__device__ __forceinline__ s8v ld8(const uint16_t* p){ return *(const s8v*)p; }
// 8-byte-aligned s8v load (for stride-36 P rows): two ds_read_b64
__device__ __forceinline__ s8v ld8u(const uint16_t* p){
  s4v lo = *(const s4v*)p; s4v hi = *(const s4v*)(p+4);
  return __builtin_shufflevector(lo, hi, 0,1,2,3,4,5,6,7);
}
#define ROWF(e2) (((e2)&3) + 8*((e2)>>2) + 4*h2)

// S memory map (u16 units), total 80800 = 161.6 KB:
//  X1S    0..12800   x1 [v][32]            ; MLP: H1 feat [v][32]
//  X2S 12800..25600  x2 [v][32]            ; MLP: G1 feat [v][32]
//  XCV 25600..38400  X  [c][400]           ; step2: P1 head ; MLP: H2' feat [v][32]
//  PBA 38400..54400  phaseL: XT+weights ; step1: P0(38400) ; step2: P1 tail + P0(40000) ; MLP: G2' feat
//  HCV 54400..67200  stats rs/cs ; step1: P1 tail ; H1 [c][400] ; MLP: folded weights+bias
//  GCV 67200..80000  G1 [c][400]
//  RINV 80000..80400, CINV 80400..80800 (bf16)
#define X1S 0
#define X2S 12800
#define XCV 25600
#define PBA 38400
#define HCV 54400
#define GCV 67200
#define RINV 80000
#define CINV 80400

__global__ __launch_bounds__(TT,2) void dymix(
    const float* __restrict__ x,
    const float* __restrict__ w1, const float* __restrict__ b1,
    const float* __restrict__ w2, const float* __restrict__ b2,
    const float* __restrict__ wm1, const float* __restrict__ bm1,
    const float* __restrict__ wm2, const float* __restrict__ bm2,
    float* __restrict__ out)
{
  __shared__ __align__(16) uint16_t S[80800];

  const int blk = blockIdx.x;
  const int xcd = blk & 7, slot = blk >> 3;    // group 12 l-blocks of each n per XCD
  const int n = xcd*4 + slot/12;
  const int l = slot - (slot/12)*12;
  const int t = threadIdx.x;
  const int wv = t >> 6;
  const int lane = t & 63;
  const int q  = lane >> 4;
  const int r  = lane & 15;
  const int h2 = lane >> 5;
  const int m32 = lane & 31;
  const long xbase = (long)n*153600 + l;

  // ---------- Phase 0: stage X -> XCV [c][400] ----------
  for (int i = t; i < 12800; i += TT) S[XCV + i] = f2bf(x[xbase + (long)i*12]);
  __syncthreads();

  // ---------- Phase L prep: XT + lin weights into PBA ----------
  for (int i = t; i < 12800; i += TT) { int v = i>>5, c = i&31; S[PBA + i] = S[XCV + c*400 + v]; }
  for (int i = t; i < 1024; i += TT) {
    int o = i>>5, c = i&31;
    S[PBA + 12800 + o*40 + c] = f2bf(w1[i]);
    S[PBA + 14080 + o*40 + c] = f2bf(w2[i]);
  }
  if (t < 32) { ((float*)(S+PBA+15360))[t] = b1[t]; ((float*)(S+PBA+15424))[t] = b2[t]; }
  __syncthreads();

  // ---------- Phase L: x1 = tanh(W1 X + b1), x2 = tanh(W2 X + b2) -> [v][32] ----------
  #pragma unroll
  for (int j = 0; j < 4; ++j) {
    int u = wv + 8*j;
    if (u < 24) {
      int nt = u >> 1, li = u & 1;
      const uint16_t* W = S + PBA + 12800 + li*1280;
      const float* bf = (const float*)(S + PBA + 15360 + li*64);
      uint16_t* dst = S + (li ? X2S : X1S);
      f16v z = {};
      #pragma unroll
      for (int kk = 0; kk < 2; ++kk) {
        s8v a = ld8(W + m32*40 + kk*16 + h2*8);
        s8v b = ld8(S + PBA + (nt*32 + m32)*32 + kk*16 + h2*8);
        z = MF32(a, b, z);
      }
      int v = nt*32 + m32;
      #pragma unroll
      for (int g = 0; g < 4; ++g) {
        union{uint16_t u4[4]; uint2 d;} pk;
        #pragma unroll
        for (int e = 0; e < 4; ++e) { int cc = 8*g + 4*h2 + e; pk.u4[e] = f2bf(tanhf(z[4*g+e] + bf[cc])); }
        *(uint2*)(dst + v*32 + 8*g + 4*h2) = pk.d;
      }
    } else if (u < 28) {
      int li = (u-24)>>1, mt = u&1;
      const uint16_t* W = S + PBA + 12800 + li*1280;
      const float* bf = (const float*)(S + PBA + 15360 + li*64);
      uint16_t* dst = S + (li ? X2S : X1S);
      s8v a = ld8(W + (mt*16 + r)*40 + q*8);
      s8v b = ld8(S + PBA + (384 + r)*32 + q*8);
      f4v z4 = {}; z4 = MF16(a, b, z4);
      union{uint16_t u4[4]; uint2 d;} pk;
      #pragma unroll
      for (int e = 0; e < 4; ++e) { int cc = mt*16 + q*4 + e; pk.u4[e] = f2bf(tanhf(z4[e] + bf[cc])); }
      *(uint2*)(dst + (384 + r)*32 + mt*16 + q*4) = pk.d;
    }
  }
  // preload MLP X b-frags from XT (PBA) into registers (XT dies when diffusion starts)
  s8v xf00, xf01, xf10, xf11, xft;
  {
    int m0 = wv;
    xf00 = ld8(S + PBA + (m0*32 + m32)*32 + h2*8);
    xf01 = ld8(S + PBA + (m0*32 + m32)*32 + 16 + h2*8);
    int m1 = (wv + 8 < 12) ? wv + 8 : wv;
    xf10 = ld8(S + PBA + (m1*32 + m32)*32 + h2*8);
    xf11 = ld8(S + PBA + (m1*32 + m32)*32 + 16 + h2*8);
    xft  = ld8(S + PBA + (384 + r)*32 + q*8);
  }
  __syncthreads();

  // ---------- Stats: rowsum/colsum of exp(A) (rs/cs fp32 in HCV region) ----------
  float* rsf = (float*)(S + HCV);
  float* csf = rsf + 400;
  for (int i = t; i < 400; i += TT) csf[i] = 0.f;
  __syncthreads();
  {
    s8v av[4]; f4v rac[4] = {{},{},{},{}};
    #pragma unroll
    for (int jj = 0; jj < 4; ++jj) { int vt = wv + 8*jj; if (vt < 25) av[jj] = ld8(S + X1S + (vt*16 + r)*32 + q*8); }
    for (int wt = 0; wt < 25; ++wt) {
      s8v b = ld8(S + X2S + (wt*16 + r)*32 + q*8);
      float cp = 0.f;
      #pragma unroll
      for (int jj = 0; jj < 4; ++jj) {
        int vt = wv + 8*jj;
        if (vt < 25) {
          f4v z = {}; z = MF16(av[jj], b, z);
          #pragma unroll
          for (int e = 0; e < 4; ++e) { float ev = __expf(z[e]); rac[jj][e] += ev; cp += ev; }
        }
      }
      cp += __shfl_xor(cp, 16); cp += __shfl_xor(cp, 32);
      if (q == 0) atomicAdd(&csf[wt*16 + r], cp);
    }
    #pragma unroll
    for (int jj = 0; jj < 4; ++jj) {
      int vt = wv + 8*jj;
      if (vt < 25) {
        #pragma unroll
        for (int e = 0; e < 4; ++e) {
          float s = rac[jj][e];
          s += __shfl_xor(s,1); s += __shfl_xor(s,2); s += __shfl_xor(s,4); s += __shfl_xor(s,8);
          if (r == 0) rsf[vt*16 + q*4 + e] = s;
        }
      }
    }
  }
  __syncthreads();
  for (int i = t; i < 400; i += TT) { S[RINV + i] = f2bf(1.f/rsf[i]); S[CINV + i] = f2bf(1.f/csf[i]); }
  __syncthreads();

  // ---------- Diffusion: wave-private producer/consumer units, ZERO intra-step barriers ----------
  // unit g = wv + 8*jj (g<26): chain = g<13?0:1, uu = g-13*chain. uu<12: 32-wide w-tile; uu==12: 16-wide tail.
  // P row stride 36 u16 (72B): 2-way bank aliasing only; b-frags via ld8u (2x ds_read_b64).
  f16v acc[4];
  for (int step = 0; step < 2; ++step) {
    { f16v zv = {}; acc[0]=zv; acc[1]=zv; acc[2]=zv; acc[3]=zv; }
    const uint16_t* AH = S + (step ? HCV : XCV);
    const uint16_t* AG = S + (step ? GCV : XCV);
    uint16_t* P0 = S + (step ? 40000 : PBA);
    uint16_t* P1 = S + (step ? XCV : 52800);
    for (int sb = 0; sb < 13; ++sb) {
      const int vbase = sb*32;
      const bool lastsb = (sb == 12);
      #pragma unroll
      for (int jj = 0; jj < 4; ++jj) {
        int g = wv + 8*jj;
        if (g >= 26) continue;
        int chain = (g < 13) ? 0 : 1;
        int uu = g - 13*chain;
        uint16_t* P = chain ? P1 : P0;
        const uint16_t* Acv = chain ? AG : AH;
        // ---- T: produce this wave's P rows ----
        if (uu < 12) {
          if (chain == 0) {
            s8v a0 = ld8(S + X1S + (vbase + m32)*32 + h2*8);
            s8v a1 = ld8(S + X1S + (vbase + m32)*32 + 16 + h2*8);
            s8v b0 = ld8(S + X2S + (uu*32 + m32)*32 + h2*8);
            s8v b1 = ld8(S + X2S + (uu*32 + m32)*32 + 16 + h2*8);
            f16v z = {}; z = MF32(a0, b0, z); z = MF32(a1, b1, z);
            uint16_t* pw = P + (uu*32 + m32)*36;
            int gmax = lastsb ? 2 : 4;
            for (int gg = 0; gg < gmax; ++gg) {
              union{uint16_t u4[4]; uint2 d;} pk;
              #pragma unroll
              for (int e = 0; e < 4; ++e) {
                int k = 8*gg + 4*h2 + e;   // k == v-row
                pk.u4[e] = f2bf(__expf(z[4*gg+e]) * bf2f(S[RINV + vbase + k]));
              }
              *(uint2*)(pw + 8*gg + 4*h2) = pk.d;
            }
          } else {
            s8v a0 = ld8(S + X1S + (uu*32 + m32)*32 + h2*8);
            s8v a1 = ld8(S + X1S + (uu*32 + m32)*32 + 16 + h2*8);
            s8v b0 = ld8(S + X2S + (vbase + m32)*32 + h2*8);
            s8v b1 = ld8(S + X2S + (vbase + m32)*32 + 16 + h2*8);
            f16v z = {}; z = MF32(a0, b0, z); z = MF32(a1, b1, z);
            bool wr = !lastsb || (m32 < 16);
            if (wr) {
              float cv = bf2f(S[CINV + vbase + m32]);
              #pragma unroll
              for (int e2 = 0; e2 < 16; ++e2) {
                int w = uu*32 + ROWF(e2);
                P[w*36 + m32] = f2bf(__expf(z[e2]) * cv);
              }
            }
          }
        } else {
          if (chain == 0) {
            int mtmax = lastsb ? 1 : 2;
            for (int mt = 0; mt < mtmax; ++mt) {
              s8v a = ld8(S + X1S + (vbase + mt*16 + r)*32 + q*8);
              s8v b = ld8(S + X2S + (384 + r)*32 + q*8);
              f4v z4 = {}; z4 = MF16(a, b, z4);
              union{uint16_t u4[4]; uint2 d;} pk;
              #pragma unroll
              for (int e = 0; e < 4; ++e) { int k = mt*16 + q*4 + e; pk.u4[e] = f2bf(__expf(z4[e]) * bf2f(S[RINV + vbase + k])); }
              *(uint2*)(P + (384 + r)*36 + mt*16 + q*4) = pk.d;
            }
            if (lastsb && lane < 16) {
              uint2 z0 = {0u,0u};
              uint16_t* pz = P + (384 + lane)*36 + 16;
              *(uint2*)(pz) = z0; *(uint2*)(pz+4) = z0; *(uint2*)(pz+8) = z0; *(uint2*)(pz+12) = z0;
            }
          } else {
            int ctmax = lastsb ? 1 : 2;
            for (int ct = 0; ct < ctmax; ++ct) {
              s8v a = ld8(S + X1S + (384 + r)*32 + q*8);
              s8v b = ld8(S + X2S + (vbase + ct*16 + r)*32 + q*8);
              f4v z4 = {}; z4 = MF16(a, b, z4);
              float cvt = bf2f(S[CINV + vbase + ct*16 + r]);
              #pragma unroll
              for (int e = 0; e < 4; ++e) P[(384 + q*4 + e)*36 + ct*16 + r] = f2bf(__expf(z4[e]) * cvt);
            }
            if (lastsb && lane < 16) {
              uint2 z0 = {0u,0u};
              uint16_t* pz = P + (384 + lane)*36 + 16;
              *(uint2*)(pz) = z0; *(uint2*)(pz+4) = z0; *(uint2*)(pz+8) = z0; *(uint2*)(pz+12) = z0;
            }
          }
        }
        // ---- GEMM: consume this wave's own P rows (in-wave lgkm ordering, no barrier) ----
        if (uu < 12) {
          int kmax = lastsb ? 1 : 2;
          for (int kk = 0; kk < kmax; ++kk) {
            s8v a = ld8(Acv + m32*400 + vbase + kk*16 + h2*8);
            s8v b = ld8u(P + (uu*32 + m32)*36 + kk*16 + h2*8);
            acc[jj] = MF32(a, b, acc[jj]);
          }
        } else {
          #pragma unroll
          for (int mt2 = 0; mt2 < 2; ++mt2) {
            s8v a = ld8(Acv + (mt2*16 + r)*400 + vbase + q*8);
            s8v b = ld8u(P + (384 + r)*36 + q*8);
            f4v c4 = { acc[jj][4*mt2+0], acc[jj][4*mt2+1], acc[jj][4*mt2+2], acc[jj][4*mt2+3] };
            c4 = MF16(a, b, c4);
            acc[jj][4*mt2+0]=c4[0]; acc[jj][4*mt2+1]=c4[1]; acc[jj][4*mt2+2]=c4[2]; acc[jj][4*mt2+3]=c4[3];
          }
        }
      } // jj
    } // sb
    __syncthreads();
    if (step == 0) {
      // epilogue: H1/G1 = AL*X + OM*acc -> HCV/GCV [c][400]
      #pragma unroll
      for (int jj = 0; jj < 4; ++jj) {
        int g = wv + 8*jj;
        if (g >= 26) continue;
        int chain = (g < 13) ? 0 : 1;
        int uu = g - 13*chain;
        uint16_t* dst = S + (chain ? GCV : HCV);
        if (uu < 12) {
          int w = uu*32 + m32;
          #pragma unroll
          for (int e2 = 0; e2 < 16; ++e2) {
            int c = ROWF(e2);
            dst[c*400 + w] = f2bf(AL*bf2f(S[XCV + c*400 + w]) + OM*acc[jj][e2]);
          }
        } else {
          int w = 384 + r;
          #pragma unroll
          for (int mt2 = 0; mt2 < 2; ++mt2)
            #pragma unroll
            for (int e = 0; e < 4; ++e) {
              int c = mt2*16 + q*4 + e;
              dst[c*400 + w] = f2bf(AL*bf2f(S[XCV + c*400 + w]) + OM*acc[jj][4*mt2+e]);
            }
        }
      }
      __syncthreads();
    }
  } // step

  // ---------- MLP prep: features to [v][32]; weights folded into HCV ----------
  for (int i = t; i < 12800; i += TT) {
    int v = i >> 5, c = i & 31;
    S[X1S + i] = S[HCV + c*400 + v];   // H1
    S[X2S + i] = S[GCV + c*400 + v];   // G1
  }
  #pragma unroll
  for (int jj = 0; jj < 4; ++jj) {
    int g = wv + 8*jj;
    if (g >= 26) continue;
    int chain = (g < 13) ? 0 : 1;
    int uu = g - 13*chain;
    uint16_t* dst = S + (chain ? PBA : XCV);   // H2' -> XCV, G2' -> PBA  (as [v][32])
    if (uu < 12) {
      int w = uu*32 + m32;
      #pragma unroll
      for (int gg = 0; gg < 4; ++gg) {
        union{uint16_t u4[4]; uint2 d;} pk;
        #pragma unroll
        for (int e = 0; e < 4; ++e) pk.u4[e] = f2bf(OM*acc[jj][4*gg+e]);
        *(uint2*)(dst + w*32 + 8*gg + 4*h2) = pk.d;
      }
    } else {
      int w = 384 + r;
      #pragma unroll
      for (int mt2 = 0; mt2 < 2; ++mt2) {
        union{uint16_t u4[4]; uint2 d;} pk;
        #pragma unroll
        for (int e = 0; e < 4; ++e) pk.u4[e] = f2bf(OM*acc[jj][4*mt2+e]);
        *(uint2*)(dst + w*32 + mt2*16 + q*4) = pk.d;
      }
    }
  }
  __syncthreads();
  for (int i = t; i < 1024; i += TT) {
    int o = i >> 5, c = i & 31;
    float h2w = wm1[o*96 + 64 + c], g2w = wm2[o*96 + 64 + c];
    S[HCV +        o*40 + c] = f2bf(wm1[o*96 + c] + wm2[o*96 + c] + AL*(h2w + g2w));
    S[HCV + 1280 + o*40 + c] = f2bf(wm1[o*96 + 32 + c]);
    S[HCV + 2560 + o*40 + c] = f2bf(h2w);
    S[HCV + 3840 + o*40 + c] = f2bf(wm2[o*96 + 32 + c]);
    S[HCV + 5120 + o*40 + c] = f2bf(g2w);
  }
  if (t < 32) ((float*)(S + HCV + 6400))[t] = bm1[t] + bm2[t];
  __syncthreads();

  // ---------- MLP + staged store to out[n][l][o][v] (coalesced) ----------
  {
    const float* boF = (const float*)(S + HCV + 6400);
    float* oSl = out + (long)(n*12 + l)*12800;
    const int fb[5] = { 0, X1S, XCV, X2S, PBA };   // X(regs), H1, H2', G1, G2'
    #pragma unroll
    for (int jm = 0; jm < 2; ++jm) {
      int m = wv + 8*jm;
      if (m < 12) {
        f16v z = {};
        #pragma unroll
        for (int p = 0; p < 5; ++p) {
          #pragma unroll
          for (int kk = 0; kk < 2; ++kk) {
            s8v a = ld8(S + HCV + p*1280 + m32*40 + kk*16 + h2*8);
            s8v b;
            if (p == 0) b = jm ? (kk ? xf11 : xf10) : (kk ? xf01 : xf00);
            else        b = ld8(S + fb[p] + (m*32 + m32)*32 + kk*16 + h2*8);
            z = MF32(a, b, z);
          }
        }
        int v = m*32 + m32;
        #pragma unroll
        for (int e2 = 0; e2 < 16; ++e2) {
          int o = ROWF(e2);
          oSl[o*400 + v] = z[e2] + boF[o];
        }
      } else if (m < 14) {
        int mt = m - 12;
        f4v z4 = {};
        #pragma unroll
        for (int p = 0; p < 5; ++p) {
          s8v a = ld8(S + HCV + p*1280 + (mt*16 + r)*40 + q*8);
          s8v b = (p == 0) ? xft : ld8(S + fb[p] + (384 + r)*32 + q*8);
          z4 = MF16(a, b, z4);
        }
        #pragma unroll
        for (int e = 0; e < 4; ++e) {
          int o = mt*16 + q*4 + e;
          oSl[o*400 + 384 + r] = z4[e] + boF[o];
        }
      }
    }
  }
}

// Cooperative in-place transpose of d_out: [n][l][o][v] -> [n][o][v][l]
__global__ __launch_bounds__(256) void finT(float* __restrict__ o) {
  cg::grid_group grid = cg::this_grid();
  int idx = blockIdx.x*256 + threadIdx.x;      // n*12800 + ov
  int n = idx / 12800, ov = idx - n*12800;
  long sb = (long)n*153600 + ov;
  float vals[12];
  #pragma unroll
  for (int l = 0; l < 12; ++l) vals[l] = o[sb + (long)l*12800];
  grid.sync();
  float4* dst = (float4*)(o + (long)idx*12);
  dst[0] = make_float4(vals[0],vals[1],vals[2],vals[3]);
  dst[1] = make_float4(vals[4],vals[5],vals[6],vals[7]);
  dst[2] = make_float4(vals[8],vals[9],vals[10],vals[11]);
}

extern "C" void kernel_launch(void* const* d_in, const int* in_sizes, int n_in,
                              void* d_out, int out_size, void* d_ws, size_t ws_size,
                              hipStream_t stream) {
  (void)in_sizes; (void)n_in; (void)out_size; (void)d_ws; (void)ws_size;
  dymix<<<dim3(384), dim3(TT), 0, stream>>>(
      (const float*)d_in[0],
      (const float*)d_in[1], (const float*)d_in[2],
      (const float*)d_in[3], (const float*)d_in[4],
      (const float*)d_in[5], (const float*)d_in[6],
      (const float*)d_in[7], (const float*)d_in[8],
      (float*)d_out);
  float* op = (float*)d_out;
  void* args[] = { &op };
  hipLaunchCooperativeKernel((void*)finT, dim3(1600), dim3(256), args, 0, stream);
}

// Round 6
// 288.129 us; speedup vs baseline: 7.1468x; 1.4330x over previous
//
#include <hip/hip_runtime.h>
#include <stdint.h>

#define TT 512
#define AL 0.05f
#define OM 0.95f
#define STRD 408   // padded [c][.] row stride: 204 dwords ≡ 12 mod 32 → even 4 dwords/bank on b128

typedef short s4v __attribute__((ext_vector_type(4)));
typedef short s8v __attribute__((ext_vector_type(8)));
typedef float f4v __attribute__((ext_vector_type(4)));
typedef float f16v __attribute__((ext_vector_type(16)));

#define MF32(a,b,c) __builtin_amdgcn_mfma_f32_32x32x16_bf16(a,b,c,0,0,0)
#define MF16(a,b,c) __builtin_amdgcn_mfma_f32_16x16x32_bf16(a,b,c,0,0,0)

__device__ __forceinline__ uint16_t f2bf(float f){ union{float f;uint32_t i;}t; t.f=f; return (uint16_t)((t.i + 0x7fffu + ((t.i>>16)&1u))>>16); }
__device__ __forceinline__ float bf2f(uint16_t h){ union{uint32_t i;float f;}t; t.i=((uint32_t)h)<<16; return t.f; }
__device__ __forceinline__ s8v ld8(const uint16_t* p){ return *(const s8v*)p; }
__device__ __forceinline__ s8v ld8u(const uint16_t* p){
  s4v lo = *(const s4v*)p; s4v hi = *(const s4v*)(p+4);
  return __builtin_shufflevector(lo, hi, 0,1,2,3,4,5,6,7);
}
#define ROWF(e2) (((e2)&3) + 8*((e2)>>2) + 4*h2)

// staging buffer for output transpose (device global — not d_ws, whose size is insufficient)
__device__ __align__(16) float gStage[32*12*12800];

// S map (u16), total 81568 = 163.1 KB:
//  X1S    0..12800   x1 [v][32]           ; MLP: H1 feat
//  X2S 12800..25600  x2 [v][32]           ; MLP: G1 feat
//  XCV 25600..38656  X  [c][408]          ; step2: P1 (25600..40000) ; MLP: H2' feat [v][32]
//  PBA 38656..54656  phaseL: XT+weights ; step1: P0(38656..53056) ; step2: P0(40256..54656) ; MLP: G2' feat
//  HCV 54656..67712  stats rs/cs ; step1: P1 tail (53056..67456) ; H1 [c][408] ; MLP: folded weights+bias
//  GCV 67712..80768  G1 [c][408]
//  RINV 80768..81168, CINV 81168..81568 (bf16)
#define X1S 0
#define X2S 12800
#define XCV 25600
#define PBA 38656
#define HCV 54656
#define GCV 67712
#define RINV 80768
#define CINV 81168

__global__ __launch_bounds__(TT,2) void dymix(
    const float* __restrict__ x,
    const float* __restrict__ w1, const float* __restrict__ b1,
    const float* __restrict__ w2, const float* __restrict__ b2,
    const float* __restrict__ wm1, const float* __restrict__ bm1,
    const float* __restrict__ wm2, const float* __restrict__ bm2)
{
  __shared__ __align__(16) uint16_t S[81568];

  const int blk = blockIdx.x;
  const int xcd = blk & 7, slot = blk >> 3;    // group 12 l-blocks of each n per XCD
  const int n = xcd*4 + slot/12;
  const int l = slot - (slot/12)*12;
  const int t = threadIdx.x;
  const int wv = t >> 6;
  const int lane = t & 63;
  const int q  = lane >> 4;
  const int r  = lane & 15;
  const int h2 = lane >> 5;
  const int m32 = lane & 31;
  const long xbase = (long)n*153600 + l;

  // ---------- Phase 0: stage X -> XCV [c][408] ----------
  for (int i = t; i < 12800; i += TT) {
    int c = i / 400, v = i - c*400;
    S[XCV + c*STRD + v] = f2bf(x[xbase + (long)i*12]);
  }
  __syncthreads();

  // ---------- Phase L prep: XT + lin weights into PBA ----------
  for (int i = t; i < 12800; i += TT) { int v = i>>5, c = i&31; S[PBA + i] = S[XCV + c*STRD + v]; }
  for (int i = t; i < 1024; i += TT) {
    int o = i>>5, c = i&31;
    S[PBA + 12800 + o*40 + c] = f2bf(w1[i]);
    S[PBA + 14080 + o*40 + c] = f2bf(w2[i]);
  }
  if (t < 32) { ((float*)(S+PBA+15360))[t] = b1[t]; ((float*)(S+PBA+15424))[t] = b2[t]; }
  __syncthreads();

  // ---------- Phase L: x1 = tanh(W1 X + b1), x2 = tanh(W2 X + b2) -> [v][32] ----------
  #pragma unroll
  for (int j = 0; j < 4; ++j) {
    int u = wv + 8*j;
    if (u < 24) {
      int nt = u >> 1, li = u & 1;
      const uint16_t* W = S + PBA + 12800 + li*1280;
      const float* bf = (const float*)(S + PBA + 15360 + li*64);
      uint16_t* dst = S + (li ? X2S : X1S);
      f16v z = {};
      #pragma unroll
      for (int kk = 0; kk < 2; ++kk) {
        s8v a = ld8(W + m32*40 + kk*16 + h2*8);
        s8v b = ld8(S + PBA + (nt*32 + m32)*32 + kk*16 + h2*8);
        z = MF32(a, b, z);
      }
      int v = nt*32 + m32;
      #pragma unroll
      for (int g = 0; g < 4; ++g) {
        union{uint16_t u4[4]; uint2 d;} pk;
        #pragma unroll
        for (int e = 0; e < 4; ++e) { int cc = 8*g + 4*h2 + e; pk.u4[e] = f2bf(tanhf(z[4*g+e] + bf[cc])); }
        *(uint2*)(dst + v*32 + 8*g + 4*h2) = pk.d;
      }
    } else if (u < 28) {
      int li = (u-24)>>1, mt = u&1;
      const uint16_t* W = S + PBA + 12800 + li*1280;
      const float* bf = (const float*)(S + PBA + 15360 + li*64);
      uint16_t* dst = S + (li ? X2S : X1S);
      s8v a = ld8(W + (mt*16 + r)*40 + q*8);
      s8v b = ld8(S + PBA + (384 + r)*32 + q*8);
      f4v z4 = {}; z4 = MF16(a, b, z4);
      union{uint16_t u4[4]; uint2 d;} pk;
      #pragma unroll
      for (int e = 0; e < 4; ++e) { int cc = mt*16 + q*4 + e; pk.u4[e] = f2bf(tanhf(z4[e] + bf[cc])); }
      *(uint2*)(dst + (384 + r)*32 + mt*16 + q*4) = pk.d;
    }
  }
  // preload MLP X b-frags from XT (XT dies when diffusion starts)
  s8v xf00, xf01, xf10, xf11, xft;
  {
    int m0 = wv;
    xf00 = ld8(S + PBA + (m0*32 + m32)*32 + h2*8);
    xf01 = ld8(S + PBA + (m0*32 + m32)*32 + 16 + h2*8);
    int m1 = (wv + 8 < 12) ? wv + 8 : wv;
    xf10 = ld8(S + PBA + (m1*32 + m32)*32 + h2*8);
    xf11 = ld8(S + PBA + (m1*32 + m32)*32 + 16 + h2*8);
    xft  = ld8(S + PBA + (384 + r)*32 + q*8);
  }
  __syncthreads();

  // ---------- Stats: rowsum/colsum of exp(A) ----------
  float* rsf = (float*)(S + HCV);
  float* csf = rsf + 400;
  for (int i = t; i < 400; i += TT) csf[i] = 0.f;
  __syncthreads();
  {
    s8v av[4]; f4v rac[4] = {{},{},{},{}};
    #pragma unroll
    for (int jj = 0; jj < 4; ++jj) { int vt = wv + 8*jj; if (vt < 25) av[jj] = ld8(S + X1S + (vt*16 + r)*32 + q*8); }
    for (int wt = 0; wt < 25; ++wt) {
      s8v b = ld8(S + X2S + (wt*16 + r)*32 + q*8);
      float cp = 0.f;
      #pragma unroll
      for (int jj = 0; jj < 4; ++jj) {
        int vt = wv + 8*jj;
        if (vt < 25) {
          f4v z = {}; z = MF16(av[jj], b, z);
          #pragma unroll
          for (int e = 0; e < 4; ++e) { float ev = __expf(z[e]); rac[jj][e] += ev; cp += ev; }
        }
      }
      cp += __shfl_xor(cp, 16); cp += __shfl_xor(cp, 32);
      if (q == 0) atomicAdd(&csf[wt*16 + r], cp);
    }
    #pragma unroll
    for (int jj = 0; jj < 4; ++jj) {
      int vt = wv + 8*jj;
      if (vt < 25) {
        #pragma unroll
        for (int e = 0; e < 4; ++e) {
          float s = rac[jj][e];
          s += __shfl_xor(s,1); s += __shfl_xor(s,2); s += __shfl_xor(s,4); s += __shfl_xor(s,8);
          if (r == 0) rsf[vt*16 + q*4 + e] = s;
        }
      }
    }
  }
  __syncthreads();
  for (int i = t; i < 400; i += TT) { S[RINV + i] = f2bf(1.f/rsf[i]); S[CINV + i] = f2bf(1.f/csf[i]); }
  __syncthreads();

  // ---------- Diffusion: wave-private producer/consumer units, zero intra-step barriers.
  // Per slab: T for all 4 units of this wave, THEN GEMM for all 4 (cross-unit ILP). ----------
  f16v acc[4];
  for (int step = 0; step < 2; ++step) {
    { f16v zv = {}; acc[0]=zv; acc[1]=zv; acc[2]=zv; acc[3]=zv; }
    const uint16_t* AH = S + (step ? HCV : XCV);
    const uint16_t* AG = S + (step ? GCV : XCV);
    uint16_t* P0 = S + (step ? 40256 : PBA);
    uint16_t* P1 = S + (step ? XCV : 53056);
    for (int sb = 0; sb < 13; ++sb) {
      const int vbase = sb*32;
      const bool lastsb = (sb == 12);
      // ---- T: produce all this wave's P rows ----
      #pragma unroll
      for (int jj = 0; jj < 4; ++jj) {
        int g = wv + 8*jj;
        if (g >= 26) continue;
        int chain = (g < 13) ? 0 : 1;
        int uu = g - 13*chain;
        uint16_t* P = chain ? P1 : P0;
        if (uu < 12) {
          if (chain == 0) {
            s8v a0 = ld8(S + X1S + (vbase + m32)*32 + h2*8);
            s8v a1 = ld8(S + X1S + (vbase + m32)*32 + 16 + h2*8);
            s8v b0 = ld8(S + X2S + (uu*32 + m32)*32 + h2*8);
            s8v b1 = ld8(S + X2S + (uu*32 + m32)*32 + 16 + h2*8);
            f16v z = {}; z = MF32(a0, b0, z); z = MF32(a1, b1, z);
            uint16_t* pw = P + (uu*32 + m32)*36;
            int gmax = lastsb ? 2 : 4;
            for (int gg = 0; gg < gmax; ++gg) {
              union{uint16_t u4[4]; uint2 d;} pk;
              #pragma unroll
              for (int e = 0; e < 4; ++e) {
                int k = 8*gg + 4*h2 + e;
                pk.u4[e] = f2bf(__expf(z[4*gg+e]) * bf2f(S[RINV + vbase + k]));
              }
              *(uint2*)(pw + 8*gg + 4*h2) = pk.d;
            }
          } else {
            s8v a0 = ld8(S + X1S + (uu*32 + m32)*32 + h2*8);
            s8v a1 = ld8(S + X1S + (uu*32 + m32)*32 + 16 + h2*8);
            s8v b0 = ld8(S + X2S + (vbase + m32)*32 + h2*8);
            s8v b1 = ld8(S + X2S + (vbase + m32)*32 + 16 + h2*8);
            f16v z = {}; z = MF32(a0, b0, z); z = MF32(a1, b1, z);
            bool wr = !lastsb || (m32 < 16);
            if (wr) {
              float cv = bf2f(S[CINV + vbase + m32]);
              #pragma unroll
              for (int e2 = 0; e2 < 16; ++e2) {
                int w = uu*32 + ROWF(e2);
                P[w*36 + m32] = f2bf(__expf(z[e2]) * cv);
              }
            }
          }
        } else {
          if (chain == 0) {
            int mtmax = lastsb ? 1 : 2;
            for (int mt = 0; mt < mtmax; ++mt) {
              s8v a = ld8(S + X1S + (vbase + mt*16 + r)*32 + q*8);
              s8v b = ld8(S + X2S + (384 + r)*32 + q*8);
              f4v z4 = {}; z4 = MF16(a, b, z4);
              union{uint16_t u4[4]; uint2 d;} pk;
              #pragma unroll
              for (int e = 0; e < 4; ++e) { int k = mt*16 + q*4 + e; pk.u4[e] = f2bf(__expf(z4[e]) * bf2f(S[RINV + vbase + k])); }
              *(uint2*)(P + (384 + r)*36 + mt*16 + q*4) = pk.d;
            }
            if (lastsb && lane < 16) {
              uint2 z0 = {0u,0u};
              uint16_t* pz = P + (384 + lane)*36 + 16;
              *(uint2*)(pz) = z0; *(uint2*)(pz+4) = z0; *(uint2*)(pz+8) = z0; *(uint2*)(pz+12) = z0;
            }
          } else {
            int ctmax = lastsb ? 1 : 2;
            for (int ct = 0; ct < ctmax; ++ct) {
              s8v a = ld8(S + X1S + (384 + r)*32 + q*8);
              s8v b = ld8(S + X2S + (vbase + ct*16 + r)*32 + q*8);
              f4v z4 = {}; z4 = MF16(a, b, z4);
              float cvt = bf2f(S[CINV + vbase + ct*16 + r]);
              #pragma unroll
              for (int e = 0; e < 4; ++e) P[(384 + q*4 + e)*36 + ct*16 + r] = f2bf(__expf(z4[e]) * cvt);
            }
            if (lastsb && lane < 16) {
              uint2 z0 = {0u,0u};
              uint16_t* pz = P + (384 + lane)*36 + 16;
              *(uint2*)(pz) = z0; *(uint2*)(pz+4) = z0; *(uint2*)(pz+8) = z0; *(uint2*)(pz+12) = z0;
            }
          }
        }
      }
      // ---- GEMM: consume all this wave's P rows ----
      #pragma unroll
      for (int jj = 0; jj < 4; ++jj) {
        int g = wv + 8*jj;
        if (g >= 26) continue;
        int chain = (g < 13) ? 0 : 1;
        int uu = g - 13*chain;
        uint16_t* P = chain ? P1 : P0;
        const uint16_t* Acv = chain ? AG : AH;
        if (uu < 12) {
          int kmax = lastsb ? 1 : 2;
          for (int kk = 0; kk < kmax; ++kk) {
            s8v a = ld8(Acv + m32*STRD + vbase + kk*16 + h2*8);
            s8v b = ld8u(P + (uu*32 + m32)*36 + kk*16 + h2*8);
            acc[jj] = MF32(a, b, acc[jj]);
          }
        } else {
          #pragma unroll
          for (int mt2 = 0; mt2 < 2; ++mt2) {
            int koff = (lastsb && q >= 2) ? 0 : q*8;   // pad bytes are never written — NaN guard (×0 in P)
            s8v a = ld8(Acv + (mt2*16 + r)*STRD + vbase + koff);
            s8v b = ld8u(P + (384 + r)*36 + q*8);
            f4v c4 = { acc[jj][4*mt2+0], acc[jj][4*mt2+1], acc[jj][4*mt2+2], acc[jj][4*mt2+3] };
            c4 = MF16(a, b, c4);
            acc[jj][4*mt2+0]=c4[0]; acc[jj][4*mt2+1]=c4[1]; acc[jj][4*mt2+2]=c4[2]; acc[jj][4*mt2+3]=c4[3];
          }
        }
      }
    } // sb
    __syncthreads();
    if (step == 0) {
      // epilogue: H1/G1 = AL*X + OM*acc -> HCV/GCV [c][408]
      #pragma unroll
      for (int jj = 0; jj < 4; ++jj) {
        int g = wv + 8*jj;
        if (g >= 26) continue;
        int chain = (g < 13) ? 0 : 1;
        int uu = g - 13*chain;
        uint16_t* dst = S + (chain ? GCV : HCV);
        if (uu < 12) {
          int w = uu*32 + m32;
          #pragma unroll
          for (int e2 = 0; e2 < 16; ++e2) {
            int c = ROWF(e2);
            dst[c*STRD + w] = f2bf(AL*bf2f(S[XCV + c*STRD + w]) + OM*acc[jj][e2]);
          }
        } else {
          int w = 384 + r;
          #pragma unroll
          for (int mt2 = 0; mt2 < 2; ++mt2)
            #pragma unroll
            for (int e = 0; e < 4; ++e) {
              int c = mt2*16 + q*4 + e;
              dst[c*STRD + w] = f2bf(AL*bf2f(S[XCV + c*STRD + w]) + OM*acc[jj][4*mt2+e]);
            }
        }
      }
      __syncthreads();
    }
  } // step

  // ---------- MLP prep: features to [v][32]; weights folded into HCV ----------
  for (int i = t; i < 12800; i += TT) {
    int v = i >> 5, c = i & 31;
    S[X1S + i] = S[HCV + c*STRD + v];   // H1
    S[X2S + i] = S[GCV + c*STRD + v];   // G1
  }
  #pragma unroll
  for (int jj = 0; jj < 4; ++jj) {
    int g = wv + 8*jj;
    if (g >= 26) continue;
    int chain = (g < 13) ? 0 : 1;
    int uu = g - 13*chain;
    uint16_t* dst = S + (chain ? PBA : XCV);   // H2' -> XCV, G2' -> PBA  (as [v][32])
    if (uu < 12) {
      int w = uu*32 + m32;
      #pragma unroll
      for (int gg = 0; gg < 4; ++gg) {
        union{uint16_t u4[4]; uint2 d;} pk;
        #pragma unroll
        for (int e = 0; e < 4; ++e) pk.u4[e] = f2bf(OM*acc[jj][4*gg+e]);
        *(uint2*)(dst + w*32 + 8*gg + 4*h2) = pk.d;
      }
    } else {
      int w = 384 + r;
      #pragma unroll
      for (int mt2 = 0; mt2 < 2; ++mt2) {
        union{uint16_t u4[4]; uint2 d;} pk;
        #pragma unroll
        for (int e = 0; e < 4; ++e) pk.u4[e] = f2bf(OM*acc[jj][4*mt2+e]);
        *(uint2*)(dst + w*32 + mt2*16 + q*4) = pk.d;
      }
    }
  }
  __syncthreads();
  for (int i = t; i < 1024; i += TT) {
    int o = i >> 5, c = i & 31;
    float h2w = wm1[o*96 + 64 + c], g2w = wm2[o*96 + 64 + c];
    S[HCV +        o*40 + c] = f2bf(wm1[o*96 + c] + wm2[o*96 + c] + AL*(h2w + g2w));
    S[HCV + 1280 + o*40 + c] = f2bf(wm1[o*96 + 32 + c]);
    S[HCV + 2560 + o*40 + c] = f2bf(h2w);
    S[HCV + 3840 + o*40 + c] = f2bf(wm2[o*96 + 32 + c]);
    S[HCV + 5120 + o*40 + c] = f2bf(g2w);
  }
  if (t < 32) ((float*)(S + HCV + 6400))[t] = bm1[t] + bm2[t];
  __syncthreads();

  // ---------- MLP + coalesced staged store to gStage[n][l][o][v] ----------
  {
    const float* boF = (const float*)(S + HCV + 6400);
    float* oSl = gStage + (long)(n*12 + l)*12800;
    const int fb[5] = { 0, X1S, XCV, X2S, PBA };   // X(regs), H1, H2', G1, G2'
    #pragma unroll
    for (int jm = 0; jm < 2; ++jm) {
      int m = wv + 8*jm;
      if (m < 12) {
        f16v z = {};
        #pragma unroll
        for (int p = 0; p < 5; ++p) {
          #pragma unroll
          for (int kk = 0; kk < 2; ++kk) {
            s8v a = ld8(S + HCV + p*1280 + m32*40 + kk*16 + h2*8);
            s8v b;
            if (p == 0) b = jm ? (kk ? xf11 : xf10) : (kk ? xf01 : xf00);
            else        b = ld8(S + fb[p] + (m*32 + m32)*32 + kk*16 + h2*8);
            z = MF32(a, b, z);
          }
        }
        int v = m*32 + m32;
        #pragma unroll
        for (int e2 = 0; e2 < 16; ++e2) {
          int o = ROWF(e2);
          oSl[o*400 + v] = z[e2] + boF[o];
        }
      } else if (m < 14) {
        int mt = m - 12;
        f4v z4 = {};
        #pragma unroll
        for (int p = 0; p < 5; ++p) {
          s8v a = ld8(S + HCV + p*1280 + (mt*16 + r)*40 + q*8);
          s8v b = (p == 0) ? xft : ld8(S + fb[p] + (384 + r)*32 + q*8);
          z4 = MF16(a, b, z4);
        }
        #pragma unroll
        for (int e = 0; e < 4; ++e) {
          int o = mt*16 + q*4 + e;
          oSl[o*400 + 384 + r] = z4[e] + boF[o];
        }
      }
    }
  }
}

// Plain transpose kernel: gStage[n][l][o][v] -> out[n][o][v][l] (both sides coalesced)
__global__ __launch_bounds__(256) void finT(float* __restrict__ out) {
  int idx = blockIdx.x*256 + threadIdx.x;      // n*12800 + ov
  int n = idx / 12800, ov = idx - n*12800;
  const float* src = gStage + (long)n*153600 + ov;
  float vals[12];
  #pragma unroll
  for (int l = 0; l < 12; ++l) vals[l] = src[(long)l*12800];
  float4* dst = (float4*)(out + (long)idx*12);
  dst[0] = make_float4(vals[0],vals[1],vals[2],vals[3]);
  dst[1] = make_float4(vals[4],vals[5],vals[6],vals[7]);
  dst[2] = make_float4(vals[8],vals[9],vals[10],vals[11]);
}

extern "C" void kernel_launch(void* const* d_in, const int* in_sizes, int n_in,
                              void* d_out, int out_size, void* d_ws, size_t ws_size,
                              hipStream_t stream) {
  (void)in_sizes; (void)n_in; (void)out_size; (void)d_ws; (void)ws_size;
  dymix<<<dim3(384), dim3(TT), 0, stream>>>(
      (const float*)d_in[0],
      (const float*)d_in[1], (const float*)d_in[2],
      (const float*)d_in[3], (const float*)d_in[4],
      (const float*)d_in[5], (const float*)d_in[6],
      (const float*)d_in[7], (const float*)d_in[8]);
  finT<<<dim3(1600), dim3(256), 0, stream>>>((float*)d_out);
}

// Round 7
// 282.245 us; speedup vs baseline: 7.2958x; 1.0208x over previous
//
#include <hip/hip_runtime.h>
#include <stdint.h>

#define TT 1024
#define AL 0.05f
#define OM 0.95f
#define STRD 408   // padded [c][.] row stride

typedef short s4v __attribute__((ext_vector_type(4)));
typedef short s8v __attribute__((ext_vector_type(8)));
typedef float f4v __attribute__((ext_vector_type(4)));
typedef float f16v __attribute__((ext_vector_type(16)));

#define MF32(a,b,c) __builtin_amdgcn_mfma_f32_32x32x16_bf16(a,b,c,0,0,0)
#define MF16(a,b,c) __builtin_amdgcn_mfma_f32_16x16x32_bf16(a,b,c,0,0,0)

__device__ __forceinline__ uint16_t f2bf(float f){ union{float f;uint32_t i;}t; t.f=f; return (uint16_t)((t.i + 0x7fffu + ((t.i>>16)&1u))>>16); }
__device__ __forceinline__ float bf2f(uint16_t h){ union{uint32_t i;float f;}t; t.i=((uint32_t)h)<<16; return t.f; }
__device__ __forceinline__ s8v ld8(const uint16_t* p){ return *(const s8v*)p; }
__device__ __forceinline__ s8v ld8u(const uint16_t* p){
  s4v lo = *(const s4v*)p; s4v hi = *(const s4v*)(p+4);
  return __builtin_shufflevector(lo, hi, 0,1,2,3,4,5,6,7);
}
#define ROWF(e2) (((e2)&3) + 8*((e2)>>2) + 4*h2)

// staging buffer for output transpose
__device__ __align__(16) float gStage[32*12*12800];

// S map (u16), total 81568 = 163.1 KB (same as round 6)
#define X1S 0
#define X2S 12800
#define XCV 25600
#define PBA 38656
#define HCV 54656
#define GCV 67712
#define RINV 80768
#define CINV 81168

__global__ __launch_bounds__(TT) void dymix(
    const float* __restrict__ x,
    const float* __restrict__ w1, const float* __restrict__ b1,
    const float* __restrict__ w2, const float* __restrict__ b2,
    const float* __restrict__ wm1, const float* __restrict__ bm1,
    const float* __restrict__ wm2, const float* __restrict__ bm2)
{
  __shared__ __align__(16) uint16_t S[81568];

  const int blk = blockIdx.x;
  const int xcd = blk & 7, slot = blk >> 3;    // group 12 l-blocks of each n per XCD
  const int n = xcd*4 + slot/12;
  const int l = slot - (slot/12)*12;
  const int t = threadIdx.x;
  const int wv = t >> 6;        // 0..15
  const int lane = t & 63;
  const int q  = lane >> 4;
  const int r  = lane & 15;
  const int h2 = lane >> 5;
  const int m32 = lane & 31;
  const long xbase = (long)n*153600 + l;

  // ---------- Phase 0: stage X -> XCV [c][408] ----------
  for (int i = t; i < 12800; i += TT) {
    int c = i / 400, v = i - c*400;
    S[XCV + c*STRD + v] = f2bf(x[xbase + (long)i*12]);
  }
  __syncthreads();

  // ---------- Phase L prep: XT + lin weights into PBA ----------
  for (int i = t; i < 12800; i += TT) { int v = i>>5, c = i&31; S[PBA + i] = S[XCV + c*STRD + v]; }
  for (int i = t; i < 1024; i += TT) {
    int o = i>>5, c = i&31;
    S[PBA + 12800 + o*40 + c] = f2bf(w1[i]);
    S[PBA + 14080 + o*40 + c] = f2bf(w2[i]);
  }
  if (t < 32) { ((float*)(S+PBA+15360))[t] = b1[t]; ((float*)(S+PBA+15424))[t] = b2[t]; }
  __syncthreads();

  // ---------- Phase L: x1 = tanh(W1 X + b1), x2 = tanh(W2 X + b2) -> [v][32] ----------
  #pragma unroll
  for (int j = 0; j < 2; ++j) {
    int u = wv + 16*j;
    if (u < 24) {
      int nt = u >> 1, li = u & 1;
      const uint16_t* W = S + PBA + 12800 + li*1280;
      const float* bf = (const float*)(S + PBA + 15360 + li*64);
      uint16_t* dst = S + (li ? X2S : X1S);
      f16v z = {};
      #pragma unroll
      for (int kk = 0; kk < 2; ++kk) {
        s8v a = ld8(W + m32*40 + kk*16 + h2*8);
        s8v b = ld8(S + PBA + (nt*32 + m32)*32 + kk*16 + h2*8);
        z = MF32(a, b, z);
      }
      int v = nt*32 + m32;
      #pragma unroll
      for (int g = 0; g < 4; ++g) {
        union{uint16_t u4[4]; uint2 d;} pk;
        #pragma unroll
        for (int e = 0; e < 4; ++e) { int cc = 8*g + 4*h2 + e; pk.u4[e] = f2bf(tanhf(z[4*g+e] + bf[cc])); }
        *(uint2*)(dst + v*32 + 8*g + 4*h2) = pk.d;
      }
    } else if (u < 28) {
      int li = (u-24)>>1, mt = u&1;
      const uint16_t* W = S + PBA + 12800 + li*1280;
      const float* bf = (const float*)(S + PBA + 15360 + li*64);
      uint16_t* dst = S + (li ? X2S : X1S);
      s8v a = ld8(W + (mt*16 + r)*40 + q*8);
      s8v b = ld8(S + PBA + (384 + r)*32 + q*8);
      f4v z4 = {}; z4 = MF16(a, b, z4);
      union{uint16_t u4[4]; uint2 d;} pk;
      #pragma unroll
      for (int e = 0; e < 4; ++e) { int cc = mt*16 + q*4 + e; pk.u4[e] = f2bf(tanhf(z4[e] + bf[cc])); }
      *(uint2*)(dst + (384 + r)*32 + mt*16 + q*4) = pk.d;
    }
  }
  // preload MLP X b-frags from XT (XT dies when diffusion starts)
  s8v xf0, xf1, xft;
  {
    int m0 = (wv < 12) ? wv : 0;
    xf0 = ld8(S + PBA + (m0*32 + m32)*32 + h2*8);
    xf1 = ld8(S + PBA + (m0*32 + m32)*32 + 16 + h2*8);
    xft = ld8(S + PBA + (384 + r)*32 + q*8);
  }
  __syncthreads();

  // ---------- Stats: rowsum/colsum of exp(A) ----------
  float* rsf = (float*)(S + HCV);
  float* csf = rsf + 400;
  for (int i = t; i < 400; i += TT) csf[i] = 0.f;
  __syncthreads();
  {
    s8v av[2]; f4v rac[2] = {{},{}};
    #pragma unroll
    for (int jj = 0; jj < 2; ++jj) { int vt = wv + 16*jj; if (vt < 25) av[jj] = ld8(S + X1S + (vt*16 + r)*32 + q*8); }
    for (int wt = 0; wt < 25; ++wt) {
      s8v b = ld8(S + X2S + (wt*16 + r)*32 + q*8);
      float cp = 0.f;
      #pragma unroll
      for (int jj = 0; jj < 2; ++jj) {
        int vt = wv + 16*jj;
        if (vt < 25) {
          f4v z = {}; z = MF16(av[jj], b, z);
          #pragma unroll
          for (int e = 0; e < 4; ++e) { float ev = __expf(z[e]); rac[jj][e] += ev; cp += ev; }
        }
      }
      cp += __shfl_xor(cp, 16); cp += __shfl_xor(cp, 32);
      if (q == 0) atomicAdd(&csf[wt*16 + r], cp);
    }
    #pragma unroll
    for (int jj = 0; jj < 2; ++jj) {
      int vt = wv + 16*jj;
      if (vt < 25) {
        #pragma unroll
        for (int e = 0; e < 4; ++e) {
          float s = rac[jj][e];
          s += __shfl_xor(s,1); s += __shfl_xor(s,2); s += __shfl_xor(s,4); s += __shfl_xor(s,8);
          if (r == 0) rsf[vt*16 + q*4 + e] = s;
        }
      }
    }
  }
  __syncthreads();
  for (int i = t; i < 400; i += TT) { S[RINV + i] = f2bf(1.f/rsf[i]); S[CINV + i] = f2bf(1.f/csf[i]); }
  __syncthreads();

  // ---------- Diffusion: wave-private producer/consumer units, zero intra-step barriers.
  // Unified T for both chains: chain1 computes A^T tiles by swapping MFMA operands,
  // so BOTH chains write P k-contiguously (4 uint2 stores — no b16 scatter). ----------
  f16v acc[2];
  for (int step = 0; step < 2; ++step) {
    { f16v zv = {}; acc[0]=zv; acc[1]=zv; }
    const uint16_t* AH = S + (step ? HCV : XCV);
    const uint16_t* AG = S + (step ? GCV : XCV);
    uint16_t* P0 = S + (step ? 40256 : PBA);
    uint16_t* P1 = S + (step ? XCV : 53056);
    for (int sb = 0; sb < 13; ++sb) {
      const int vbase = sb*32;
      const bool lastsb = (sb == 12);
      // ---- T: produce this wave's P rows (both chains, unified) ----
      #pragma unroll
      for (int jj = 0; jj < 2; ++jj) {
        int g = wv + 16*jj;
        if (g >= 26) continue;
        int chain = (g < 13) ? 0 : 1;
        int uu = g - 13*chain;
        uint16_t* P = chain ? P1 : P0;
        const uint16_t* sa = S + (chain ? X2S : X1S);   // m-operand: v-slab rows
        const uint16_t* sb2 = S + (chain ? X1S : X2S);  // n-operand: w-tile rows
        const int scl = chain ? CINV : RINV;
        if (uu < 12) {
          s8v a0 = ld8(sa + (vbase + m32)*32 + h2*8);
          s8v a1 = ld8(sa + (vbase + m32)*32 + 16 + h2*8);
          s8v b0 = ld8(sb2 + (uu*32 + m32)*32 + h2*8);
          s8v b1 = ld8(sb2 + (uu*32 + m32)*32 + 16 + h2*8);
          f16v z = {}; z = MF32(a0, b0, z); z = MF32(a1, b1, z);
          uint16_t* pw = P + (uu*32 + m32)*36;
          int gmax = lastsb ? 2 : 4;
          for (int gg = 0; gg < gmax; ++gg) {
            union{uint16_t u4[4]; uint2 d;} pk;
            #pragma unroll
            for (int e = 0; e < 4; ++e) {
              int k = 8*gg + 4*h2 + e;     // k == v-offset in slab
              pk.u4[e] = f2bf(__expf(z[4*gg+e]) * bf2f(S[scl + vbase + k]));
            }
            *(uint2*)(pw + 8*gg + 4*h2) = pk.d;
          }
        } else {
          int ctmax = lastsb ? 1 : 2;
          for (int ct = 0; ct < ctmax; ++ct) {
            s8v a = ld8(sa + (vbase + ct*16 + r)*32 + q*8);
            s8v b = ld8(sb2 + (384 + r)*32 + q*8);
            f4v z4 = {}; z4 = MF16(a, b, z4);
            union{uint16_t u4[4]; uint2 d;} pk;
            #pragma unroll
            for (int e = 0; e < 4; ++e) { int k = ct*16 + q*4 + e; pk.u4[e] = f2bf(__expf(z4[e]) * bf2f(S[scl + vbase + k])); }
            *(uint2*)(P + (384 + r)*36 + ct*16 + q*4) = pk.d;
          }
          if (lastsb && lane < 16) {
            uint2 z0 = {0u,0u};
            uint16_t* pz = P + (384 + lane)*36 + 16;
            *(uint2*)(pz) = z0; *(uint2*)(pz+4) = z0; *(uint2*)(pz+8) = z0; *(uint2*)(pz+12) = z0;
          }
        }
      }
      // ---- GEMM: consume this wave's own P rows (in-wave lgkm ordering, no barrier) ----
      #pragma unroll
      for (int jj = 0; jj < 2; ++jj) {
        int g = wv + 16*jj;
        if (g >= 26) continue;
        int chain = (g < 13) ? 0 : 1;
        int uu = g - 13*chain;
        uint16_t* P = chain ? P1 : P0;
        const uint16_t* Acv = chain ? AG : AH;
        if (uu < 12) {
          int kmax = lastsb ? 1 : 2;
          for (int kk = 0; kk < kmax; ++kk) {
            s8v a = ld8(Acv + m32*STRD + vbase + kk*16 + h2*8);
            s8v b = ld8u(P + (uu*32 + m32)*36 + kk*16 + h2*8);
            acc[jj] = MF32(a, b, acc[jj]);
          }
        } else {
          #pragma unroll
          for (int mt2 = 0; mt2 < 2; ++mt2) {
            int koff = (lastsb && q >= 2) ? 0 : q*8;   // pad cols never written — NaN guard (×0 in P)
            s8v a = ld8(Acv + (mt2*16 + r)*STRD + vbase + koff);
            s8v b = ld8u(P + (384 + r)*36 + q*8);
            f4v c4 = { acc[jj][4*mt2+0], acc[jj][4*mt2+1], acc[jj][4*mt2+2], acc[jj][4*mt2+3] };
            c4 = MF16(a, b, c4);
            acc[jj][4*mt2+0]=c4[0]; acc[jj][4*mt2+1]=c4[1]; acc[jj][4*mt2+2]=c4[2]; acc[jj][4*mt2+3]=c4[3];
          }
        }
      }
    } // sb
    __syncthreads();
    if (step == 0) {
      // epilogue: H1/G1 = AL*X + OM*acc -> HCV/GCV [c][408]
      #pragma unroll
      for (int jj = 0; jj < 2; ++jj) {
        int g = wv + 16*jj;
        if (g >= 26) continue;
        int chain = (g < 13) ? 0 : 1;
        int uu = g - 13*chain;
        uint16_t* dst = S + (chain ? GCV : HCV);
        if (uu < 12) {
          int w = uu*32 + m32;
          #pragma unroll
          for (int e2 = 0; e2 < 16; ++e2) {
            int c = ROWF(e2);
            dst[c*STRD + w] = f2bf(AL*bf2f(S[XCV + c*STRD + w]) + OM*acc[jj][e2]);
          }
        } else {
          int w = 384 + r;
          #pragma unroll
          for (int mt2 = 0; mt2 < 2; ++mt2)
            #pragma unroll
            for (int e = 0; e < 4; ++e) {
              int c = mt2*16 + q*4 + e;
              dst[c*STRD + w] = f2bf(AL*bf2f(S[XCV + c*STRD + w]) + OM*acc[jj][4*mt2+e]);
            }
        }
      }
      __syncthreads();
    }
  } // step

  // ---------- MLP prep: features to [v][32]; weights folded into HCV ----------
  for (int i = t; i < 12800; i += TT) {
    int v = i >> 5, c = i & 31;
    S[X1S + i] = S[HCV + c*STRD + v];   // H1
    S[X2S + i] = S[GCV + c*STRD + v];   // G1
  }
  #pragma unroll
  for (int jj = 0; jj < 2; ++jj) {
    int g = wv + 16*jj;
    if (g >= 26) continue;
    int chain = (g < 13) ? 0 : 1;
    int uu = g - 13*chain;
    uint16_t* dst = S + (chain ? PBA : XCV);   // H2' -> XCV, G2' -> PBA  (as [v][32])
    if (uu < 12) {
      int w = uu*32 + m32;
      #pragma unroll
      for (int gg = 0; gg < 4; ++gg) {
        union{uint16_t u4[4]; uint2 d;} pk;
        #pragma unroll
        for (int e = 0; e < 4; ++e) pk.u4[e] = f2bf(OM*acc[jj][4*gg+e]);
        *(uint2*)(dst + w*32 + 8*gg + 4*h2) = pk.d;
      }
    } else {
      int w = 384 + r;
      #pragma unroll
      for (int mt2 = 0; mt2 < 2; ++mt2) {
        union{uint16_t u4[4]; uint2 d;} pk;
        #pragma unroll
        for (int e = 0; e < 4; ++e) pk.u4[e] = f2bf(OM*acc[jj][4*mt2+e]);
        *(uint2*)(dst + w*32 + mt2*16 + q*4) = pk.d;
      }
    }
  }
  __syncthreads();
  for (int i = t; i < 1024; i += TT) {
    int o = i >> 5, c = i & 31;
    float h2w = wm1[o*96 + 64 + c], g2w = wm2[o*96 + 64 + c];
    S[HCV +        o*40 + c] = f2bf(wm1[o*96 + c] + wm2[o*96 + c] + AL*(h2w + g2w));
    S[HCV + 1280 + o*40 + c] = f2bf(wm1[o*96 + 32 + c]);
    S[HCV + 2560 + o*40 + c] = f2bf(h2w);
    S[HCV + 3840 + o*40 + c] = f2bf(wm2[o*96 + 32 + c]);
    S[HCV + 5120 + o*40 + c] = f2bf(g2w);
  }
  if (t < 32) ((float*)(S + HCV + 6400))[t] = bm1[t] + bm2[t];
  __syncthreads();

  // ---------- MLP + coalesced staged store to gStage[n][l][o][v] ----------
  {
    const float* boF = (const float*)(S + HCV + 6400);
    float* oSl = gStage + (long)(n*12 + l)*12800;
    const int fb[5] = { 0, X1S, XCV, X2S, PBA };   // X(regs), H1, H2', G1, G2'
    int m = wv;
    if (m < 12) {
      f16v z = {};
      #pragma unroll
      for (int p = 0; p < 5; ++p) {
        #pragma unroll
        for (int kk = 0; kk < 2; ++kk) {
          s8v a = ld8(S + HCV + p*1280 + m32*40 + kk*16 + h2*8);
          s8v b;
          if (p == 0) b = kk ? xf1 : xf0;
          else        b = ld8(S + fb[p] + (m*32 + m32)*32 + kk*16 + h2*8);
          z = MF32(a, b, z);
        }
      }
      int v = m*32 + m32;
      #pragma unroll
      for (int e2 = 0; e2 < 16; ++e2) {
        int o = ROWF(e2);
        oSl[o*400 + v] = z[e2] + boF[o];
      }
    } else if (m < 14) {
      int mt = m - 12;
      f4v z4 = {};
      #pragma unroll
      for (int p = 0; p < 5; ++p) {
        s8v a = ld8(S + HCV + p*1280 + (mt*16 + r)*40 + q*8);
        s8v b = (p == 0) ? xft : ld8(S + fb[p] + (384 + r)*32 + q*8);
        z4 = MF16(a, b, z4);
      }
      #pragma unroll
      for (int e = 0; e < 4; ++e) {
        int o = mt*16 + q*4 + e;
        oSl[o*400 + 384 + r] = z4[e] + boF[o];
      }
    }
  }
}

// Plain transpose kernel: gStage[n][l][o][v] -> out[n][o][v][l] (both sides coalesced)
__global__ __launch_bounds__(256) void finT(float* __restrict__ out) {
  int idx = blockIdx.x*256 + threadIdx.x;      // n*12800 + ov
  int n = idx / 12800, ov = idx - n*12800;
  const float* src = gStage + (long)n*153600 + ov;
  float vals[12];
  #pragma unroll
  for (int l = 0; l < 12; ++l) vals[l] = src[(long)l*12800];
  float4* dst = (float4*)(out + (long)idx*12);
  dst[0] = make_float4(vals[0],vals[1],vals[2],vals[3]);
  dst[1] = make_float4(vals[4],vals[5],vals[6],vals[7]);
  dst[2] = make_float4(vals[8],vals[9],vals[10],vals[11]);
}

extern "C" void kernel_launch(void* const* d_in, const int* in_sizes, int n_in,
                              void* d_out, int out_size, void* d_ws, size_t ws_size,
                              hipStream_t stream) {
  (void)in_sizes; (void)n_in; (void)out_size; (void)d_ws; (void)ws_size;
  dymix<<<dim3(384), dim3(TT), 0, stream>>>(
      (const float*)d_in[0],
      (const float*)d_in[1], (const float*)d_in[2],
      (const float*)d_in[3], (const float*)d_in[4],
      (const float*)d_in[5], (const float*)d_in[6],
      (const float*)d_in[7], (const float*)d_in[8]);
  finT<<<dim3(1600), dim3(256), 0, stream>>>((float*)d_out);
}